// Round 9
// baseline (702.408 us; speedup 1.0000x reference)
//
#include <hip/hip_runtime.h>
#include <hip/hip_bf16.h>

#define DM 768
#define NH 12
#define TB 2
#define TT 4096
#define MM (TB*TT)        // 8192 tokens
#define NQKV (3*DM)       // 2304
#define NW (DM*DM)        // 589824
#define NX (MM*DM)        // 6291456
#define CEQ 0.18033688f   // 0.125 * log2(e), folded into Q

typedef unsigned short u16;
typedef short s16x8 __attribute__((ext_vector_type(8)));
typedef unsigned short u16x8 __attribute__((ext_vector_type(8)));
typedef float f32x4 __attribute__((ext_vector_type(4)));
typedef float f32x16 __attribute__((ext_vector_type(16)));
typedef unsigned u32x4 __attribute__((ext_vector_type(4)));

#if __has_builtin(__builtin_amdgcn_exp2f)
#define EXP2 __builtin_amdgcn_exp2f
#else
#define EXP2 exp2f
#endif

__device__ __forceinline__ u16 f2bf(float f) {
  unsigned u = __builtin_bit_cast(unsigned, f);
  unsigned r = (u + 0x7FFFu + ((u >> 16) & 1u)) >> 16;
  return (u16)r;
}

__device__ __forceinline__ unsigned cvtpk(float lo, float hi) {
  unsigned r;
  asm("v_cvt_pk_bf16_f32 %0, %1, %2" : "=v"(r) : "v"(lo), "v"(hi));
  return r;
}

// async global(16B/lane) -> LDS (wave-uniform base + lane*16)
__device__ __forceinline__ void gload16(const void* g, void* l) {
  __builtin_amdgcn_global_load_lds(
      (const __attribute__((address_space(1))) void*)g,
      (__attribute__((address_space(3))) void*)l, 16, 0, 0);
}

// permlane32_swap(a,b) -> r0 = {l<32: a[l], l>=32: b[l-32]}
//                         r1 = {l<32: a[l+32], l>=32: b[l]}
__device__ __forceinline__ void plswap(unsigned a, unsigned b, unsigned& r0, unsigned& r1) {
#if __has_builtin(__builtin_amdgcn_permlane32_swap)
  auto rr = __builtin_amdgcn_permlane32_swap(a, b, false, false);
  unsigned tmp[2];
  __builtin_memcpy(tmp, &rr, 8);
  r0 = tmp[0]; r1 = tmp[1];
#else
  int hi_ = (threadIdx.x >> 5) & 1;
  unsigned bx = (unsigned)__shfl_xor((int)b, 32, 64);
  unsigned ax = (unsigned)__shfl_xor((int)a, 32, 64);
  r0 = hi_ ? bx : a;
  r1 = hi_ ? b : ax;
#endif
}

__device__ __forceinline__ float xhalf_sum(float v) {
  unsigned a = __builtin_bit_cast(unsigned, v), r0, r1;
  plswap(a, a, r0, r1);
  return __builtin_bit_cast(float, r0) + __builtin_bit_cast(float, r1);
}

// Repack one 32-key block of P^T (f32x16 per lane, key=crow(r,hi)=(r&3)+8*(r>>2)+4*hi)
// into two PV B-operand fragments (keys 0..15 -> fa, keys 16..31 -> fb).
__device__ __forceinline__ void repack2(const f32x16& sv, s16x8& fa, s16x8& fb) {
  {
    unsigned cA0 = cvtpk(sv[0], sv[1]),  cA1 = cvtpk(sv[2], sv[3]);
    unsigned cB0 = cvtpk(sv[4], sv[5]),  cB1 = cvtpk(sv[6], sv[7]);
    unsigned w0, w1, w2, w3;
    plswap(cA0, cB0, w0, w2);
    plswap(cA1, cB1, w1, w3);
    u32x4 w = {w0, w1, w2, w3};
    fa = __builtin_bit_cast(s16x8, w);
  }
  {
    unsigned cA0 = cvtpk(sv[8], sv[9]),   cA1 = cvtpk(sv[10], sv[11]);
    unsigned cB0 = cvtpk(sv[12], sv[13]), cB1 = cvtpk(sv[14], sv[15]);
    unsigned w0, w1, w2, w3;
    plswap(cA0, cB0, w0, w2);
    plswap(cA1, cB1, w1, w3);
    u32x4 w = {w0, w1, w2, w3};
    fb = __builtin_bit_cast(s16x8, w);
  }
}

// ---------------- cast / pack kernel ----------------
__global__ __launch_bounds__(256) void cast_prep(
    const float* __restrict__ x, const float* __restrict__ wq,
    const float* __restrict__ wk, const float* __restrict__ wv,
    const float* __restrict__ wo, const float* __restrict__ bq,
    const float* __restrict__ bk, const float* __restrict__ bv,
    u16* __restrict__ xb, u16* __restrict__ wqkvb, u16* __restrict__ wob,
    float* __restrict__ bqkv) {
  int g = blockIdx.x * 256 + threadIdx.x;
  int e = g * 4;
  const float* src;
  u16* dst;
  if (e < NX) { src = x + e; dst = xb + e; }
  else {
    int e2 = e - NX;
    if (e2 < 3*NW) {
      const float* w = (e2 < NW) ? wq : (e2 < 2*NW ? wk : wv);
      int base = (e2 < NW) ? 0 : (e2 < 2*NW ? NW : 2*NW);
      src = w + (e2 - base); dst = wqkvb + e2;
    } else { int e3 = e2 - 3*NW; src = wo + e3; dst = wob + e3; }
  }
  float4 v = *(const float4*)src;
  ushort4 p;
  p.x = f2bf(v.x); p.y = f2bf(v.y); p.z = f2bf(v.z); p.w = f2bf(v.w);
  *(ushort4*)dst = p;
  if (blockIdx.x == 0) {
    for (int i = threadIdx.x; i < NQKV; i += 256)
      bqkv[i] = (i < DM) ? bq[i] : (i < 2*DM ? bk[i-DM] : bv[i-2*DM]);
  }
}

// ---------------- fused QKV GEMM: C = Xb @ Wqkv^T + b ----------------------
// gload_lds double-buffered staging; Q scaled by CEQ; V stored transposed.
__global__ __launch_bounds__(256, 3) void gemm_qkv(
    const u16* __restrict__ A, const u16* __restrict__ W,
    const float* __restrict__ bias,
    u16* __restrict__ qb, u16* __restrict__ kb, u16* __restrict__ vt) {
  __shared__ __align__(16) u16 As[2][128*32], Bs[2][128*32];
  const int tid = threadIdx.x, lane = tid & 63, wave = tid >> 6;
  const int rg = lane & 15, cg = lane >> 4;
  // XCD-chunked swizzle: 1152 blocks = 8 * 144 -> each XCD owns 8 full A-rows
  int lin = blockIdx.y * 18 + blockIdx.x;
  int swz = (lin & 7) * 144 + (lin >> 3);
  const int m0 = (swz / 18) * 128, n0 = (swz % 18) * 128;
  const int wm = (wave >> 1) * 64, wn = (wave & 1) * 64;
  f32x4 acc[4][4];
#pragma unroll
  for (int i = 0; i < 4; i++)
#pragma unroll
    for (int j = 0; j < 4; j++) acc[i][j] = (f32x4){0.f,0.f,0.f,0.f};

  const u16* ga = A + (size_t)(m0 + (tid >> 2)) * DM + (tid & 3) * 8;
  const u16* gb = W + (size_t)(n0 + (tid >> 2)) * DM + (tid & 3) * 8;
  auto stage = [&](int kt, int buf) {
    int ko = kt * 32;
    char* la = (char*)&As[buf][0] + wave * 1024;
    char* lb = (char*)&Bs[buf][0] + wave * 1024;
    gload16(ga + ko,                    la);
    gload16(ga + (size_t)64*DM + ko,    la + 4096);
    gload16(gb + ko,                    lb);
    gload16(gb + (size_t)64*DM + ko,    lb + 4096);
  };

  stage(0, 0);
  __syncthreads();
  const int NT = DM / 32;  // 24
  int cur = 0;
  for (int kt = 0; kt < NT; ++kt) {
    if (kt + 1 < NT) stage(kt + 1, cur ^ 1);
    s16x8 af[4], bfv[4];
#pragma unroll
    for (int i = 0; i < 4; i++) af[i]  = *(const s16x8*)&As[cur][(wm + i*16 + rg)*32 + cg*8];
#pragma unroll
    for (int i = 0; i < 4; i++) bfv[i] = *(const s16x8*)&Bs[cur][(wn + i*16 + rg)*32 + cg*8];
    __builtin_amdgcn_s_setprio(1);
#pragma unroll
    for (int mi = 0; mi < 4; mi++)
#pragma unroll
      for (int ni = 0; ni < 4; ni++)
        acc[mi][ni] = __builtin_amdgcn_mfma_f32_16x16x32_bf16(af[mi], bfv[ni], acc[mi][ni], 0, 0, 0);
    __builtin_amdgcn_s_setprio(0);
    __syncthreads();
    cur ^= 1;
  }

#pragma unroll
  for (int ni = 0; ni < 4; ni++) {
    int o = n0 + wn + ni*16 + rg;
    float bia = bias[o];
    int mat = o / DM, d = o % DM;
    int head = d >> 6, dh = d & 63;
    if (mat == 2) {
      // V stored transposed: vt[(bh*64+dh)*TT + t], 4 consecutive t
#pragma unroll
      for (int mi = 0; mi < 4; mi++) {
        int m = m0 + wm + mi*16 + cg*4;
        int b = m >> 12, t = m & 4095;
        ushort4 pv;
        pv.x = f2bf(acc[mi][ni][0] + bia);
        pv.y = f2bf(acc[mi][ni][1] + bia);
        pv.z = f2bf(acc[mi][ni][2] + bia);
        pv.w = f2bf(acc[mi][ni][3] + bia);
        *(ushort4*)&vt[((size_t)((b*NH + head)*64 + dh))*TT + t] = pv;
      }
    } else {
      u16* outp = mat ? kb : qb;
      float sc = mat ? 1.0f : CEQ;   // fold softmax scale*log2e into Q
#pragma unroll
      for (int mi = 0; mi < 4; mi++) {
#pragma unroll
        for (int r = 0; r < 4; r++) {
          int m = m0 + wm + mi*16 + cg*4 + r;
          int b = m >> 12, t = m & 4095;
          outp[((size_t)((b*NH + head)*TT + t))*64 + dh] = f2bf((acc[mi][ni][r] + bia) * sc);
        }
      }
    }
  }
}

// ---------------- flash attention v8: 2-stage pipeline ---------------------
// attn4 structure + software pipeline: QK^T(kt+1) issued BEFORE softmax(kt)
// so the MFMA pipe runs under the exp2/repack VALU burst. 3 staging buffers;
// stage() issues K loads before V loads; end-of-iter s_waitcnt vmcnt(2)
// guarantees K(kt+2) + V(kt+1) landed while V(kt+2) stays in flight.
__global__ __launch_bounds__(256, 3) void attn8(
    const u16* __restrict__ qg, const u16* __restrict__ kg,
    const u16* __restrict__ vtg, u16* __restrict__ h) {
  __shared__ __align__(16) char smem[49152];   // 3 x (K 8KB + V 8KB); epilogue reuses
  const int tid = threadIdx.x, lane = tid & 63, wave = tid >> 6;
  const int ql = lane & 31, hi = lane >> 5;
  // XCD-bijective swizzle: 768 blocks = 8 XCD * 96
  int lin = blockIdx.y * 32 + blockIdx.x;
  int swz = (lin & 7) * 96 + (lin >> 3);
  int qt = swz & 31, bh = swz >> 5;
  const int b = bh / NH, head = bh % NH;
  const size_t hb = (size_t)bh * TT * 64;

  // ---- Q fragments (one-time strided read; Q pre-scaled by CEQ) ----
  const int qrow = qt * 128 + wave * 32 + ql;
  const u16* qp = qg + hb + (size_t)qrow * 64 + hi * 8;
  s16x8 qf[4];
#pragma unroll
  for (int ds = 0; ds < 4; ++ds) qf[ds] = *(const s16x8*)(qp + ds * 16);

  // ---- staging geometry (linear LDS dest, XOR-swizzled source) ----
  const int lr = lane >> 3;
  const int lc = ((lane & 7) ^ lr) * 16;
  const char* kSrc = (const char*)(kg + hb) + lr * 128 + lc;
  const char* vSrc = (const char*)(vtg + hb) + (size_t)lr * 8192 + lc;
  auto stage = [&](int kt, int buf) {
    char* lk = smem + buf * 16384 + wave * 2048;
    char* lv = lk + 8192;
    const char* gk = kSrc + (size_t)kt * 8192 + wave * 2048;
    const char* gv = vSrc + (size_t)kt * 128 + (size_t)wave * 131072;
    gload16(gk,          lk);          // K first: needed one iter earlier
    gload16(gk + 1024,   lk + 1024);
    gload16(gv,          lv);          // V last: may stay in flight longer
    gload16(gv + 65536,  lv + 1024);
  };

  f32x16 o0 = {}, o1 = {};
  float L = 0.f;
  const int swb = (ql & 7) << 4;
  const int NKT = TT / 64;  // 64

  // prologue: tiles 0,1 issued; wait all but V(1) -> K0,V0,K1 ready
  stage(0, 0);
  stage(1, 1);
  asm volatile("s_waitcnt vmcnt(2)" ::: "memory");
  __builtin_amdgcn_s_barrier();

  f32x16 sA0, sA1, sB0, sB1;
  {
    const char* bk_ = smem + ql * 128;
    s16x8 kf0[4], kf1[4];
#pragma unroll
    for (int ds = 0; ds < 4; ++ds) {
      kf0[ds] = *(const s16x8*)(bk_ +        ((ds*32 + hi*16) ^ swb));
      kf1[ds] = *(const s16x8*)(bk_ + 4096 + ((ds*32 + hi*16) ^ swb));
    }
    sA0 = (f32x16){}; sA1 = (f32x16){};
    __builtin_amdgcn_s_setprio(1);
#pragma unroll
    for (int ds = 0; ds < 4; ++ds) {
      sA0 = __builtin_amdgcn_mfma_f32_32x32x16_bf16(kf0[ds], qf[ds], sA0, 0, 0, 0);
      sA1 = __builtin_amdgcn_mfma_f32_32x32x16_bf16(kf1[ds], qf[ds], sA1, 0, 0, 0);
    }
    __builtin_amdgcn_s_setprio(0);
  }

  int cur = 0;
  auto body = [&](int j, f32x16& c0, f32x16& c1, f32x16& n0, f32x16& n1) {
    int sb = cur + 2; if (sb >= 3) sb -= 3;
    if (j + 2 < NKT) stage(j + 2, sb);
    int nx = cur + 1; if (nx >= 3) nx -= 3;

    // V fragments of tile j (ready since previous barrier)
    const char* bv_ = smem + cur * 16384 + 8192 + ql * 128;
    s16x8 vf0[4], vf1[4];
#pragma unroll
    for (int ks = 0; ks < 4; ++ks) {
      vf0[ks] = *(const s16x8*)(bv_ +        ((ks*32 + hi*16) ^ swb));
      vf1[ks] = *(const s16x8*)(bv_ + 4096 + ((ks*32 + hi*16) ^ swb));
    }

    // QK^T for tile j+1 -> next-state (K(j+1) guaranteed by last barrier);
    // runs on the MFMA pipe underneath the softmax VALU below.
    if (j + 1 < NKT) {
      const char* bk_ = smem + nx * 16384 + ql * 128;
      s16x8 kf0[4], kf1[4];
#pragma unroll
      for (int ds = 0; ds < 4; ++ds) {
        kf0[ds] = *(const s16x8*)(bk_ +        ((ds*32 + hi*16) ^ swb));
        kf1[ds] = *(const s16x8*)(bk_ + 4096 + ((ds*32 + hi*16) ^ swb));
      }
      n0 = (f32x16){}; n1 = (f32x16){};
      __builtin_amdgcn_s_setprio(1);
#pragma unroll
      for (int ds = 0; ds < 4; ++ds) {
        n0 = __builtin_amdgcn_mfma_f32_32x32x16_bf16(kf0[ds], qf[ds], n0, 0, 0, 0);
        n1 = __builtin_amdgcn_mfma_f32_32x32x16_bf16(kf1[ds], qf[ds], n1, 0, 0, 0);
      }
      __builtin_amdgcn_s_setprio(0);
    }

    // softmax numerator of tile j (independent of the QK above)
#pragma unroll
    for (int i = 0; i < 16; ++i) c0[i] = EXP2(c0[i]);
#pragma unroll
    for (int i = 0; i < 16; ++i) c1[i] = EXP2(c1[i]);
    f32x16 u = c0 + c1;
    float a0 = u[0] + u[8],  a1 = u[1] + u[9],  a2 = u[2] + u[10], a3 = u[3] + u[11];
    float a4 = u[4] + u[12], a5 = u[5] + u[13], a6 = u[6] + u[14], a7 = u[7] + u[15];
    a0 += a4; a1 += a5; a2 += a6; a3 += a7;
    a0 += a2; a1 += a3;
    L += a0 + a1;

    // repack P^T -> PV B-fragments
    s16x8 pf[4];
    repack2(c0, pf[0], pf[1]);
    repack2(c1, pf[2], pf[3]);

    // O^T += V^T(j) · P(j)
    __builtin_amdgcn_s_setprio(1);
#pragma unroll
    for (int ks = 0; ks < 4; ++ks) {
      o0 = __builtin_amdgcn_mfma_f32_32x32x16_bf16(vf0[ks], pf[ks], o0, 0, 0, 0);
      o1 = __builtin_amdgcn_mfma_f32_32x32x16_bf16(vf1[ks], pf[ks], o1, 0, 0, 0);
    }
    __builtin_amdgcn_s_setprio(0);

    if (j + 2 < NKT) {
      asm volatile("s_waitcnt vmcnt(2)" ::: "memory");  // K(j+2),V(j+1) landed
    } else {
      asm volatile("s_waitcnt vmcnt(0)" ::: "memory");
    }
    __builtin_amdgcn_s_barrier();
    cur = nx;
  };

  for (int j = 0; j < NKT; j += 2) {
    body(j,     sA0, sA1, sB0, sB1);
    body(j + 1, sB0, sB1, sA0, sA1);
  }

  // epilogue: cross-half L, normalize, bf16-pack, LDS transpose, store
  float Lt = xhalf_sum(L);
  float inv = 1.f / Lt;
  u16 (*ot)[32][72] = (u16(*)[32][72])smem;   // reuse stage LDS (all waves synced)
#pragma unroll
  for (int db = 0; db < 2; ++db) {
    const f32x16& ov = db ? o1 : o0;
#pragma unroll
    for (int i = 0; i < 8; ++i) {
      unsigned w = cvtpk(ov[2*i] * inv, ov[2*i+1] * inv);
      int d = db*32 + ((2*i) & 3) + 8*((2*i) >> 2) + 4*hi;
      *(unsigned*)&ot[wave][ql][d] = w;
    }
  }
  __syncthreads();
  const u16* rowp = &ot[wave][ql][hi*32];
  u32x4 r0 = *(const u32x4*)(rowp);
  u32x4 r1 = *(const u32x4*)(rowp + 8);
  u32x4 r2 = *(const u32x4*)(rowp + 16);
  u32x4 r3 = *(const u32x4*)(rowp + 24);
  u16* dst = h + (size_t)(b*TT + qrow) * DM + head*64 + hi*32;
  *(u32x4*)(dst)      = r0;
  *(u32x4*)(dst + 8)  = r1;
  *(u32x4*)(dst + 16) = r2;
  *(u32x4*)(dst + 24) = r3;
}

// ---------------- output projection: out = H @ Wo^T + bo (fp32) -----------
__global__ __launch_bounds__(256, 3) void gemm_proj(
    const u16* __restrict__ A, const u16* __restrict__ W,
    const float* __restrict__ bias, float* __restrict__ out) {
  __shared__ __align__(16) u16 As[2][128*32], Bs[2][128*32];
  const int tid = threadIdx.x, lane = tid & 63, wave = tid >> 6;
  const int rg = lane & 15, cg = lane >> 4;
  // XCD-chunked swizzle: 384 blocks = 8 * 48
  int lin = blockIdx.y * 6 + blockIdx.x;
  int swz = (lin & 7) * 48 + (lin >> 3);
  const int m0 = (swz / 6) * 128, n0 = (swz % 6) * 128;
  const int wm = (wave >> 1) * 64, wn = (wave & 1) * 64;
  f32x4 acc[4][4];
#pragma unroll
  for (int i = 0; i < 4; i++)
#pragma unroll
    for (int j = 0; j < 4; j++) acc[i][j] = (f32x4){0.f,0.f,0.f,0.f};

  const u16* ga = A + (size_t)(m0 + (tid >> 2)) * DM + (tid & 3) * 8;
  const u16* gb = W + (size_t)(n0 + (tid >> 2)) * DM + (tid & 3) * 8;
  auto stage = [&](int kt, int buf) {
    int ko = kt * 32;
    char* la = (char*)&As[buf][0] + wave * 1024;
    char* lb = (char*)&Bs[buf][0] + wave * 1024;
    gload16(ga + ko,                    la);
    gload16(ga + (size_t)64*DM + ko,    la + 4096);
    gload16(gb + ko,                    lb);
    gload16(gb + (size_t)64*DM + ko,    lb + 4096);
  };

  stage(0, 0);
  __syncthreads();
  const int NT = DM / 32;
  int cur = 0;
  for (int kt = 0; kt < NT; ++kt) {
    if (kt + 1 < NT) stage(kt + 1, cur ^ 1);
    s16x8 af[4], bfv[4];
#pragma unroll
    for (int i = 0; i < 4; i++) af[i]  = *(const s16x8*)&As[cur][(wm + i*16 + rg)*32 + cg*8];
#pragma unroll
    for (int i = 0; i < 4; i++) bfv[i] = *(const s16x8*)&Bs[cur][(wn + i*16 + rg)*32 + cg*8];
    __builtin_amdgcn_s_setprio(1);
#pragma unroll
    for (int mi = 0; mi < 4; mi++)
#pragma unroll
      for (int ni = 0; ni < 4; ni++)
        acc[mi][ni] = __builtin_amdgcn_mfma_f32_16x16x32_bf16(af[mi], bfv[ni], acc[mi][ni], 0, 0, 0);
    __builtin_amdgcn_s_setprio(0);
    __syncthreads();
    cur ^= 1;
  }
#pragma unroll
  for (int ni = 0; ni < 4; ni++) {
    int o = n0 + wn + ni*16 + rg;
    float bia = bias[o];
#pragma unroll
    for (int mi = 0; mi < 4; mi++) {
#pragma unroll
      for (int r = 0; r < 4; r++) {
        int m = m0 + wm + mi*16 + cg*4 + r;
        out[(size_t)m * DM + o] = acc[mi][ni][r] + bia;
      }
    }
  }
}

extern "C" void kernel_launch(void* const* d_in, const int* in_sizes, int n_in,
                              void* d_out, int out_size, void* d_ws, size_t ws_size,
                              hipStream_t stream) {
  (void)in_sizes; (void)n_in; (void)out_size; (void)ws_size;
  const float* x  = (const float*)d_in[0];
  const float* Wq = (const float*)d_in[1];
  const float* bq = (const float*)d_in[2];
  const float* Wk = (const float*)d_in[3];
  const float* bk = (const float*)d_in[4];
  const float* Wv = (const float*)d_in[5];
  const float* bv = (const float*)d_in[6];
  const float* Wo = (const float*)d_in[7];
  const float* bo = (const float*)d_in[8];
  float* out = (float*)d_out;

  char* ws = (char*)d_ws;
  size_t off = 0;
  auto alloc = [&](size_t bytes) {
    char* p = ws + off;
    off = (off + bytes + 255) & ~(size_t)255;
    return p;
  };
  u16*   xb    = (u16*)alloc((size_t)NX * 2);      // reused as attn output H
  u16*   wqkvb = (u16*)alloc((size_t)3 * NW * 2);
  u16*   wob   = (u16*)alloc((size_t)NW * 2);
  float* bqkv  = (float*)alloc((size_t)NQKV * 4);
  u16*   qb    = (u16*)alloc((size_t)NX * 2);
  u16*   kb    = (u16*)alloc((size_t)NX * 2);
  u16*   vtb   = (u16*)alloc((size_t)NX * 2);
  u16*   hbuf  = xb;  // xb dead after gemm_qkv

  cast_prep<<<(NX + 4*NW) / 4 / 256, 256, 0, stream>>>(x, Wq, Wk, Wv, Wo, bq, bk, bv,
                                                       xb, wqkvb, wob, bqkv);
  gemm_qkv<<<dim3(18, 64), 256, 0, stream>>>(xb, wqkvb, bqkv, qb, kb, vtb);
  attn8<<<dim3(32, TB*NH), 256, 0, stream>>>(qb, kb, vtb, hbuf);
  gemm_proj<<<dim3(6, 64), 256, 0, stream>>>(hbuf, wob, bo, out);
}

// Round 10
// 400.780 us; speedup vs baseline: 1.7526x; 1.7526x over previous
//
#include <hip/hip_runtime.h>
#include <hip/hip_bf16.h>

#define DM 768
#define NH 12
#define TB 2
#define TT 4096
#define MM (TB*TT)        // 8192 tokens
#define NQKV (3*DM)       // 2304
#define NW (DM*DM)        // 589824
#define NX (MM*DM)        // 6291456
#define CEQ 0.18033688f   // 0.125 * log2(e), folded into Q

typedef unsigned short u16;
typedef short s16x8 __attribute__((ext_vector_type(8)));
typedef unsigned short u16x8 __attribute__((ext_vector_type(8)));
typedef float f32x4 __attribute__((ext_vector_type(4)));
typedef float f32x16 __attribute__((ext_vector_type(16)));
typedef unsigned u32x4 __attribute__((ext_vector_type(4)));

#if __has_builtin(__builtin_amdgcn_exp2f)
#define EXP2 __builtin_amdgcn_exp2f
#else
#define EXP2 exp2f
#endif

__device__ __forceinline__ u16 f2bf(float f) {
  unsigned u = __builtin_bit_cast(unsigned, f);
  unsigned r = (u + 0x7FFFu + ((u >> 16) & 1u)) >> 16;
  return (u16)r;
}

__device__ __forceinline__ unsigned cvtpk(float lo, float hi) {
  unsigned r;
  asm("v_cvt_pk_bf16_f32 %0, %1, %2" : "=v"(r) : "v"(lo), "v"(hi));
  return r;
}

// async global(16B/lane) -> LDS (wave-uniform base + lane*16)
__device__ __forceinline__ void gload16(const void* g, void* l) {
  __builtin_amdgcn_global_load_lds(
      (const __attribute__((address_space(1))) void*)g,
      (__attribute__((address_space(3))) void*)l, 16, 0, 0);
}

// permlane32_swap(a,b) -> r0 = {l<32: a[l], l>=32: b[l-32]}
//                         r1 = {l<32: a[l+32], l>=32: b[l]}
__device__ __forceinline__ void plswap(unsigned a, unsigned b, unsigned& r0, unsigned& r1) {
#if __has_builtin(__builtin_amdgcn_permlane32_swap)
  auto rr = __builtin_amdgcn_permlane32_swap(a, b, false, false);
  unsigned tmp[2];
  __builtin_memcpy(tmp, &rr, 8);
  r0 = tmp[0]; r1 = tmp[1];
#else
  int hi_ = (threadIdx.x >> 5) & 1;
  unsigned bx = (unsigned)__shfl_xor((int)b, 32, 64);
  unsigned ax = (unsigned)__shfl_xor((int)a, 32, 64);
  r0 = hi_ ? bx : a;
  r1 = hi_ ? b : ax;
#endif
}

__device__ __forceinline__ float xhalf_sum(float v) {
  unsigned a = __builtin_bit_cast(unsigned, v), r0, r1;
  plswap(a, a, r0, r1);
  return __builtin_bit_cast(float, r0) + __builtin_bit_cast(float, r1);
}

// Repack one 32-key block of P^T (f32x16 per lane, key=crow(r,hi)=(r&3)+8*(r>>2)+4*hi)
// into two PV B-operand fragments (keys 0..15 -> fa, keys 16..31 -> fb).
__device__ __forceinline__ void repack2(const f32x16& sv, s16x8& fa, s16x8& fb) {
  {
    unsigned cA0 = cvtpk(sv[0], sv[1]),  cA1 = cvtpk(sv[2], sv[3]);
    unsigned cB0 = cvtpk(sv[4], sv[5]),  cB1 = cvtpk(sv[6], sv[7]);
    unsigned w0, w1, w2, w3;
    plswap(cA0, cB0, w0, w2);
    plswap(cA1, cB1, w1, w3);
    u32x4 w = {w0, w1, w2, w3};
    fa = __builtin_bit_cast(s16x8, w);
  }
  {
    unsigned cA0 = cvtpk(sv[8], sv[9]),   cA1 = cvtpk(sv[10], sv[11]);
    unsigned cB0 = cvtpk(sv[12], sv[13]), cB1 = cvtpk(sv[14], sv[15]);
    unsigned w0, w1, w2, w3;
    plswap(cA0, cB0, w0, w2);
    plswap(cA1, cB1, w1, w3);
    u32x4 w = {w0, w1, w2, w3};
    fb = __builtin_bit_cast(s16x8, w);
  }
}

// ---------------- cast / pack kernel ----------------
__global__ __launch_bounds__(256) void cast_prep(
    const float* __restrict__ x, const float* __restrict__ wq,
    const float* __restrict__ wk, const float* __restrict__ wv,
    const float* __restrict__ wo, const float* __restrict__ bq,
    const float* __restrict__ bk, const float* __restrict__ bv,
    u16* __restrict__ xb, u16* __restrict__ wqkvb, u16* __restrict__ wob,
    float* __restrict__ bqkv) {
  int g = blockIdx.x * 256 + threadIdx.x;
  int e = g * 4;
  const float* src;
  u16* dst;
  if (e < NX) { src = x + e; dst = xb + e; }
  else {
    int e2 = e - NX;
    if (e2 < 3*NW) {
      const float* w = (e2 < NW) ? wq : (e2 < 2*NW ? wk : wv);
      int base = (e2 < NW) ? 0 : (e2 < 2*NW ? NW : 2*NW);
      src = w + (e2 - base); dst = wqkvb + e2;
    } else { int e3 = e2 - 3*NW; src = wo + e3; dst = wob + e3; }
  }
  float4 v = *(const float4*)src;
  ushort4 p;
  p.x = f2bf(v.x); p.y = f2bf(v.y); p.z = f2bf(v.z); p.w = f2bf(v.w);
  *(ushort4*)dst = p;
  if (blockIdx.x == 0) {
    for (int i = threadIdx.x; i < NQKV; i += 256)
      bqkv[i] = (i < DM) ? bq[i] : (i < 2*DM ? bk[i-DM] : bv[i-2*DM]);
  }
}

// ---------------- fused QKV GEMM: C = Xb @ Wqkv^T + b ----------------------
__global__ __launch_bounds__(256, 3) void gemm_qkv(
    const u16* __restrict__ A, const u16* __restrict__ W,
    const float* __restrict__ bias,
    u16* __restrict__ qb, u16* __restrict__ kb, u16* __restrict__ vt) {
  __shared__ __align__(16) u16 As[2][128*32], Bs[2][128*32];
  const int tid = threadIdx.x, lane = tid & 63, wave = tid >> 6;
  const int rg = lane & 15, cg = lane >> 4;
  int lin = blockIdx.y * 18 + blockIdx.x;
  int swz = (lin & 7) * 144 + (lin >> 3);
  const int m0 = (swz / 18) * 128, n0 = (swz % 18) * 128;
  const int wm = (wave >> 1) * 64, wn = (wave & 1) * 64;
  f32x4 acc[4][4];
#pragma unroll
  for (int i = 0; i < 4; i++)
#pragma unroll
    for (int j = 0; j < 4; j++) acc[i][j] = (f32x4){0.f,0.f,0.f,0.f};

  const u16* ga = A + (size_t)(m0 + (tid >> 2)) * DM + (tid & 3) * 8;
  const u16* gb = W + (size_t)(n0 + (tid >> 2)) * DM + (tid & 3) * 8;
  auto stage = [&](int kt, int buf) {
    int ko = kt * 32;
    char* la = (char*)&As[buf][0] + wave * 1024;
    char* lb = (char*)&Bs[buf][0] + wave * 1024;
    gload16(ga + ko,                    la);
    gload16(ga + (size_t)64*DM + ko,    la + 4096);
    gload16(gb + ko,                    lb);
    gload16(gb + (size_t)64*DM + ko,    lb + 4096);
  };

  stage(0, 0);
  __syncthreads();
  const int NT = DM / 32;  // 24
  int cur = 0;
  for (int kt = 0; kt < NT; ++kt) {
    if (kt + 1 < NT) stage(kt + 1, cur ^ 1);
    s16x8 af[4], bfv[4];
#pragma unroll
    for (int i = 0; i < 4; i++) af[i]  = *(const s16x8*)&As[cur][(wm + i*16 + rg)*32 + cg*8];
#pragma unroll
    for (int i = 0; i < 4; i++) bfv[i] = *(const s16x8*)&Bs[cur][(wn + i*16 + rg)*32 + cg*8];
    __builtin_amdgcn_s_setprio(1);
#pragma unroll
    for (int mi = 0; mi < 4; mi++)
#pragma unroll
      for (int ni = 0; ni < 4; ni++)
        acc[mi][ni] = __builtin_amdgcn_mfma_f32_16x16x32_bf16(af[mi], bfv[ni], acc[mi][ni], 0, 0, 0);
    __builtin_amdgcn_s_setprio(0);
    __syncthreads();
    cur ^= 1;
  }

#pragma unroll
  for (int ni = 0; ni < 4; ni++) {
    int o = n0 + wn + ni*16 + rg;
    float bia = bias[o];
    int mat = o / DM, d = o % DM;
    int head = d >> 6, dh = d & 63;
    if (mat == 2) {
#pragma unroll
      for (int mi = 0; mi < 4; mi++) {
        int m = m0 + wm + mi*16 + cg*4;
        int b = m >> 12, t = m & 4095;
        ushort4 pv;
        pv.x = f2bf(acc[mi][ni][0] + bia);
        pv.y = f2bf(acc[mi][ni][1] + bia);
        pv.z = f2bf(acc[mi][ni][2] + bia);
        pv.w = f2bf(acc[mi][ni][3] + bia);
        *(ushort4*)&vt[((size_t)((b*NH + head)*64 + dh))*TT + t] = pv;
      }
    } else {
      u16* outp = mat ? kb : qb;
      float sc = mat ? 1.0f : CEQ;   // fold softmax scale*log2e into Q
#pragma unroll
      for (int mi = 0; mi < 4; mi++) {
#pragma unroll
        for (int r = 0; r < 4; r++) {
          int m = m0 + wm + mi*16 + cg*4 + r;
          int b = m >> 12, t = m & 4095;
          outp[((size_t)((b*NH + head)*TT + t))*64 + dh] = f2bf((acc[mi][ni][r] + bia) * sc);
        }
      }
    }
  }
}

// ---------------- flash attention v9: 2-stage pipeline, manual unroll ------
// attn4 + QK^T(j+1) issued before softmax(j). States sA/sB are NAMED locals
// (statically indexed everywhere) so they live in registers (rule #20 fix
// for attn8's localMem catastrophe). 3 buffers, counted vmcnt(2): at every
// barrier, V(j) and K(j+1) are complete; V(j+2)/K(j+2) stay in flight.
#define ATTN_LOADVF(bvp)                                                      \
  s16x8 vf0[4], vf1[4];                                                       \
  _Pragma("unroll")                                                           \
  for (int ks = 0; ks < 4; ++ks) {                                            \
    vf0[ks] = *(const s16x8*)((bvp) +        ((ks*32 + hi*16) ^ swb));        \
    vf1[ks] = *(const s16x8*)((bvp) + 4096 + ((ks*32 + hi*16) ^ swb));        \
  }

#define ATTN_QK(bkp, d0, d1)                                                  \
  {                                                                           \
    s16x8 kf0[4], kf1[4];                                                     \
    _Pragma("unroll")                                                         \
    for (int ds = 0; ds < 4; ++ds) {                                          \
      kf0[ds] = *(const s16x8*)((bkp) +        ((ds*32 + hi*16) ^ swb));      \
      kf1[ds] = *(const s16x8*)((bkp) + 4096 + ((ds*32 + hi*16) ^ swb));      \
    }                                                                         \
    d0 = (f32x16){}; d1 = (f32x16){};                                         \
    _Pragma("unroll")                                                         \
    for (int ds = 0; ds < 4; ++ds) {                                          \
      d0 = __builtin_amdgcn_mfma_f32_32x32x16_bf16(kf0[ds], qf[ds], d0, 0, 0, 0); \
      d1 = __builtin_amdgcn_mfma_f32_32x32x16_bf16(kf1[ds], qf[ds], d1, 0, 0, 0); \
    }                                                                         \
  }

#define ATTN_SMPV(c0, c1)                                                     \
  {                                                                           \
    _Pragma("unroll")                                                         \
    for (int i = 0; i < 16; ++i) c0[i] = EXP2(c0[i]);                         \
    _Pragma("unroll")                                                         \
    for (int i = 0; i < 16; ++i) c1[i] = EXP2(c1[i]);                         \
    f32x16 u = c0 + c1;                                                       \
    float a0 = u[0] + u[8],  a1 = u[1] + u[9],  a2 = u[2] + u[10], a3 = u[3] + u[11]; \
    float a4 = u[4] + u[12], a5 = u[5] + u[13], a6 = u[6] + u[14], a7 = u[7] + u[15]; \
    a0 += a4; a1 += a5; a2 += a6; a3 += a7;                                   \
    a0 += a2; a1 += a3;                                                       \
    L += a0 + a1;                                                             \
    s16x8 pf0, pf1, pf2, pf3;                                                 \
    repack2(c0, pf0, pf1);                                                    \
    repack2(c1, pf2, pf3);                                                    \
    __builtin_amdgcn_s_setprio(1);                                            \
    o0 = __builtin_amdgcn_mfma_f32_32x32x16_bf16(vf0[0], pf0, o0, 0, 0, 0);   \
    o1 = __builtin_amdgcn_mfma_f32_32x32x16_bf16(vf1[0], pf0, o1, 0, 0, 0);   \
    o0 = __builtin_amdgcn_mfma_f32_32x32x16_bf16(vf0[1], pf1, o0, 0, 0, 0);   \
    o1 = __builtin_amdgcn_mfma_f32_32x32x16_bf16(vf1[1], pf1, o1, 0, 0, 0);   \
    o0 = __builtin_amdgcn_mfma_f32_32x32x16_bf16(vf0[2], pf2, o0, 0, 0, 0);   \
    o1 = __builtin_amdgcn_mfma_f32_32x32x16_bf16(vf1[2], pf2, o1, 0, 0, 0);   \
    o0 = __builtin_amdgcn_mfma_f32_32x32x16_bf16(vf0[3], pf3, o0, 0, 0, 0);   \
    o1 = __builtin_amdgcn_mfma_f32_32x32x16_bf16(vf1[3], pf3, o1, 0, 0, 0);   \
    __builtin_amdgcn_s_setprio(0);                                            \
  }

__global__ __launch_bounds__(256, 3) void attn9(
    const u16* __restrict__ qg, const u16* __restrict__ kg,
    const u16* __restrict__ vtg, u16* __restrict__ h) {
  __shared__ __align__(16) char smem[49152];   // 3 x (K 8KB + V 8KB); epilogue reuses
  const int tid = threadIdx.x, lane = tid & 63, wave = tid >> 6;
  const int ql = lane & 31, hi = lane >> 5;
  // XCD-bijective swizzle: 768 blocks = 8 XCD * 96
  int lin = blockIdx.y * 32 + blockIdx.x;
  int swz = (lin & 7) * 96 + (lin >> 3);
  int qt = swz & 31, bh = swz >> 5;
  const int b = bh / NH, head = bh % NH;
  const size_t hb = (size_t)bh * TT * 64;

  // ---- Q fragments (one-time strided read; Q pre-scaled by CEQ) ----
  const int qrow = qt * 128 + wave * 32 + ql;
  const u16* qp = qg + hb + (size_t)qrow * 64 + hi * 8;
  s16x8 qf[4];
#pragma unroll
  for (int ds = 0; ds < 4; ++ds) qf[ds] = *(const s16x8*)(qp + ds * 16);

  // ---- staging geometry (linear LDS dest, XOR-swizzled source) ----
  const int lr = lane >> 3;
  const int lc = ((lane & 7) ^ lr) * 16;
  const char* kSrc = (const char*)(kg + hb) + lr * 128 + lc;
  const char* vSrc = (const char*)(vtg + hb) + (size_t)lr * 8192 + lc;
  auto stage = [&](int kt, int buf) {
    char* lk = smem + buf * 16384 + wave * 2048;
    char* lv = lk + 8192;
    const char* gk = kSrc + (size_t)kt * 8192 + wave * 2048;
    const char* gv = vSrc + (size_t)kt * 128 + (size_t)wave * 131072;
    gload16(gk,          lk);          // K first: needed one iter earlier
    gload16(gk + 1024,   lk + 1024);
    gload16(gv,          lv);          // V last: may stay in flight longer
    gload16(gv + 65536,  lv + 1024);
  };

  f32x16 o0 = {}, o1 = {};
  float L = 0.f;
  const int swb = (ql & 7) << 4;
  const int NKT = TT / 64;  // 64

  // prologue: tiles 0,1 issued; vmcnt(2) -> K0,V0,K1 ready (V1 in flight)
  stage(0, 0);
  stage(1, 1);
  asm volatile("s_waitcnt vmcnt(2)" ::: "memory");
  __builtin_amdgcn_s_barrier();

  f32x16 sA0, sA1, sB0, sB1;
  {
    const char* bk0 = smem + ql * 128;
    ATTN_QK(bk0, sA0, sA1)
  }

  int cur = 0;
  for (int j = 0; j < NKT; j += 2) {
    // ---------------- body A (tile j): consume sA, produce sB --------------
    {
      int sb = cur + 2; if (sb >= 3) sb -= 3;
      if (j + 2 < NKT) stage(j + 2, sb);
      int nx = cur + 1; if (nx >= 3) nx -= 3;
      const char* bv_ = smem + cur * 16384 + 8192 + ql * 128;
      ATTN_LOADVF(bv_)
      {  // QK^T(j+1) under softmax(j): always valid here (j+1 <= NKT-1)
        const char* bk_ = smem + nx * 16384 + ql * 128;
        __builtin_amdgcn_s_setprio(1);
        ATTN_QK(bk_, sB0, sB1)
        __builtin_amdgcn_s_setprio(0);
      }
      ATTN_SMPV(sA0, sA1)
      if (j + 2 < NKT) {
        asm volatile("s_waitcnt vmcnt(2)" ::: "memory");
      } else {
        asm volatile("s_waitcnt vmcnt(0)" ::: "memory");
      }
      __builtin_amdgcn_s_barrier();
      cur = nx;
    }
    // ---------------- body B (tile j+1): consume sB, produce sA ------------
    {
      int jj = j + 1;
      int sb = cur + 2; if (sb >= 3) sb -= 3;
      if (jj + 2 < NKT) stage(jj + 2, sb);
      int nx = cur + 1; if (nx >= 3) nx -= 3;
      const char* bv_ = smem + cur * 16384 + 8192 + ql * 128;
      ATTN_LOADVF(bv_)
      if (jj + 1 < NKT) {  // skip on the final tile
        const char* bk_ = smem + nx * 16384 + ql * 128;
        __builtin_amdgcn_s_setprio(1);
        ATTN_QK(bk_, sA0, sA1)
        __builtin_amdgcn_s_setprio(0);
      }
      ATTN_SMPV(sB0, sB1)
      if (jj + 2 < NKT) {
        asm volatile("s_waitcnt vmcnt(2)" ::: "memory");
      } else {
        asm volatile("s_waitcnt vmcnt(0)" ::: "memory");
      }
      __builtin_amdgcn_s_barrier();
      cur = nx;
    }
  }

  // epilogue: cross-half L, normalize, bf16-pack, LDS transpose, store
  float Lt = xhalf_sum(L);
  float inv = 1.f / Lt;
  u16 (*ot)[32][72] = (u16(*)[32][72])smem;   // reuse stage LDS (all waves synced)
#pragma unroll
  for (int db = 0; db < 2; ++db) {
    const f32x16& ov = db ? o1 : o0;
#pragma unroll
    for (int i = 0; i < 8; ++i) {
      unsigned w = cvtpk(ov[2*i] * inv, ov[2*i+1] * inv);
      int d = db*32 + ((2*i) & 3) + 8*((2*i) >> 2) + 4*hi;
      *(unsigned*)&ot[wave][ql][d] = w;
    }
  }
  __syncthreads();
  const u16* rowp = &ot[wave][ql][hi*32];
  u32x4 r0 = *(const u32x4*)(rowp);
  u32x4 r1 = *(const u32x4*)(rowp + 8);
  u32x4 r2 = *(const u32x4*)(rowp + 16);
  u32x4 r3 = *(const u32x4*)(rowp + 24);
  u16* dst = h + (size_t)(b*TT + qrow) * DM + head*64 + hi*32;
  *(u32x4*)(dst)      = r0;
  *(u32x4*)(dst + 8)  = r1;
  *(u32x4*)(dst + 16) = r2;
  *(u32x4*)(dst + 24) = r3;
}

// ---------------- output projection: out = H @ Wo^T + bo (fp32) -----------
__global__ __launch_bounds__(256, 3) void gemm_proj(
    const u16* __restrict__ A, const u16* __restrict__ W,
    const float* __restrict__ bias, float* __restrict__ out) {
  __shared__ __align__(16) u16 As[2][128*32], Bs[2][128*32];
  const int tid = threadIdx.x, lane = tid & 63, wave = tid >> 6;
  const int rg = lane & 15, cg = lane >> 4;
  int lin = blockIdx.y * 6 + blockIdx.x;
  int swz = (lin & 7) * 48 + (lin >> 3);
  const int m0 = (swz / 6) * 128, n0 = (swz % 6) * 128;
  const int wm = (wave >> 1) * 64, wn = (wave & 1) * 64;
  f32x4 acc[4][4];
#pragma unroll
  for (int i = 0; i < 4; i++)
#pragma unroll
    for (int j = 0; j < 4; j++) acc[i][j] = (f32x4){0.f,0.f,0.f,0.f};

  const u16* ga = A + (size_t)(m0 + (tid >> 2)) * DM + (tid & 3) * 8;
  const u16* gb = W + (size_t)(n0 + (tid >> 2)) * DM + (tid & 3) * 8;
  auto stage = [&](int kt, int buf) {
    int ko = kt * 32;
    char* la = (char*)&As[buf][0] + wave * 1024;
    char* lb = (char*)&Bs[buf][0] + wave * 1024;
    gload16(ga + ko,                    la);
    gload16(ga + (size_t)64*DM + ko,    la + 4096);
    gload16(gb + ko,                    lb);
    gload16(gb + (size_t)64*DM + ko,    lb + 4096);
  };

  stage(0, 0);
  __syncthreads();
  const int NT = DM / 32;
  int cur = 0;
  for (int kt = 0; kt < NT; ++kt) {
    if (kt + 1 < NT) stage(kt + 1, cur ^ 1);
    s16x8 af[4], bfv[4];
#pragma unroll
    for (int i = 0; i < 4; i++) af[i]  = *(const s16x8*)&As[cur][(wm + i*16 + rg)*32 + cg*8];
#pragma unroll
    for (int i = 0; i < 4; i++) bfv[i] = *(const s16x8*)&Bs[cur][(wn + i*16 + rg)*32 + cg*8];
    __builtin_amdgcn_s_setprio(1);
#pragma unroll
    for (int mi = 0; mi < 4; mi++)
#pragma unroll
      for (int ni = 0; ni < 4; ni++)
        acc[mi][ni] = __builtin_amdgcn_mfma_f32_16x16x32_bf16(af[mi], bfv[ni], acc[mi][ni], 0, 0, 0);
    __builtin_amdgcn_s_setprio(0);
    __syncthreads();
    cur ^= 1;
  }
#pragma unroll
  for (int ni = 0; ni < 4; ni++) {
    int o = n0 + wn + ni*16 + rg;
    float bia = bias[o];
#pragma unroll
    for (int mi = 0; mi < 4; mi++) {
#pragma unroll
      for (int r = 0; r < 4; r++) {
        int m = m0 + wm + mi*16 + cg*4 + r;
        out[(size_t)m * DM + o] = acc[mi][ni][r] + bia;
      }
    }
  }
}

extern "C" void kernel_launch(void* const* d_in, const int* in_sizes, int n_in,
                              void* d_out, int out_size, void* d_ws, size_t ws_size,
                              hipStream_t stream) {
  (void)in_sizes; (void)n_in; (void)out_size; (void)ws_size;
  const float* x  = (const float*)d_in[0];
  const float* Wq = (const float*)d_in[1];
  const float* bq = (const float*)d_in[2];
  const float* Wk = (const float*)d_in[3];
  const float* bk = (const float*)d_in[4];
  const float* Wv = (const float*)d_in[5];
  const float* bv = (const float*)d_in[6];
  const float* Wo = (const float*)d_in[7];
  const float* bo = (const float*)d_in[8];
  float* out = (float*)d_out;

  char* ws = (char*)d_ws;
  size_t off = 0;
  auto alloc = [&](size_t bytes) {
    char* p = ws + off;
    off = (off + bytes + 255) & ~(size_t)255;
    return p;
  };
  u16*   xb    = (u16*)alloc((size_t)NX * 2);      // reused as attn output H
  u16*   wqkvb = (u16*)alloc((size_t)3 * NW * 2);
  u16*   wob   = (u16*)alloc((size_t)NW * 2);
  float* bqkv  = (float*)alloc((size_t)NQKV * 4);
  u16*   qb    = (u16*)alloc((size_t)NX * 2);
  u16*   kb    = (u16*)alloc((size_t)NX * 2);
  u16*   vtb   = (u16*)alloc((size_t)NX * 2);
  u16*   hbuf  = xb;  // xb dead after gemm_qkv

  cast_prep<<<(NX + 4*NW) / 4 / 256, 256, 0, stream>>>(x, Wq, Wk, Wv, Wo, bq, bk, bv,
                                                       xb, wqkvb, wob, bqkv);
  gemm_qkv<<<dim3(18, 64), 256, 0, stream>>>(xb, wqkvb, bqkv, qb, kb, vtb);
  attn9<<<dim3(32, TB*NH), 256, 0, stream>>>(qb, kb, vtb, hbuf);
  gemm_proj<<<dim3(6, 64), 256, 0, stream>>>(hbuf, wob, bo, out);
}

// Round 11
// 202.820 us; speedup vs baseline: 3.4632x; 1.9760x over previous
//
#include <hip/hip_runtime.h>
#include <hip/hip_bf16.h>

#define DM 768
#define NH 12
#define TB 2
#define TT 4096
#define MM (TB*TT)        // 8192 tokens
#define NQKV (3*DM)       // 2304
#define NW (DM*DM)        // 589824
#define NX (MM*DM)        // 6291456
#define CEQ 0.18033688f   // 0.125 * log2(e), folded into Q

typedef unsigned short u16;
typedef short s16x8 __attribute__((ext_vector_type(8)));
typedef unsigned short u16x8 __attribute__((ext_vector_type(8)));
typedef float f32x4 __attribute__((ext_vector_type(4)));
typedef float f32x16 __attribute__((ext_vector_type(16)));
typedef unsigned u32x4 __attribute__((ext_vector_type(4)));

#if __has_builtin(__builtin_amdgcn_exp2f)
#define EXP2 __builtin_amdgcn_exp2f
#else
#define EXP2 exp2f
#endif

__device__ __forceinline__ u16 f2bf(float f) {
  unsigned u = __builtin_bit_cast(unsigned, f);
  unsigned r = (u + 0x7FFFu + ((u >> 16) & 1u)) >> 16;
  return (u16)r;
}

__device__ __forceinline__ unsigned cvtpk(float lo, float hi) {
  unsigned r;
  asm("v_cvt_pk_bf16_f32 %0, %1, %2" : "=v"(r) : "v"(lo), "v"(hi));
  return r;
}

// async global(16B/lane) -> LDS (wave-uniform base + lane*16)
__device__ __forceinline__ void gload16(const void* g, void* l) {
  __builtin_amdgcn_global_load_lds(
      (const __attribute__((address_space(1))) void*)g,
      (__attribute__((address_space(3))) void*)l, 16, 0, 0);
}

// permlane32_swap(a,b) -> r0 = {l<32: a[l], l>=32: b[l-32]}
//                         r1 = {l<32: a[l+32], l>=32: b[l]}
__device__ __forceinline__ void plswap(unsigned a, unsigned b, unsigned& r0, unsigned& r1) {
#if __has_builtin(__builtin_amdgcn_permlane32_swap)
  auto rr = __builtin_amdgcn_permlane32_swap(a, b, false, false);
  unsigned tmp[2];
  __builtin_memcpy(tmp, &rr, 8);
  r0 = tmp[0]; r1 = tmp[1];
#else
  int hi_ = (threadIdx.x >> 5) & 1;
  unsigned bx = (unsigned)__shfl_xor((int)b, 32, 64);
  unsigned ax = (unsigned)__shfl_xor((int)a, 32, 64);
  r0 = hi_ ? bx : a;
  r1 = hi_ ? b : ax;
#endif
}

__device__ __forceinline__ float xhalf_sum(float v) {
  unsigned a = __builtin_bit_cast(unsigned, v), r0, r1;
  plswap(a, a, r0, r1);
  return __builtin_bit_cast(float, r0) + __builtin_bit_cast(float, r1);
}

// Repack one 32-key block of P^T (f32x16 per lane, key=crow(r,hi)=(r&3)+8*(r>>2)+4*hi)
// into two PV B-operand fragments (keys 0..15 -> fa, keys 16..31 -> fb).
__device__ __forceinline__ void repack2(const f32x16& sv, s16x8& fa, s16x8& fb) {
  {
    unsigned cA0 = cvtpk(sv[0], sv[1]),  cA1 = cvtpk(sv[2], sv[3]);
    unsigned cB0 = cvtpk(sv[4], sv[5]),  cB1 = cvtpk(sv[6], sv[7]);
    unsigned w0, w1, w2, w3;
    plswap(cA0, cB0, w0, w2);
    plswap(cA1, cB1, w1, w3);
    u32x4 w = {w0, w1, w2, w3};
    fa = __builtin_bit_cast(s16x8, w);
  }
  {
    unsigned cA0 = cvtpk(sv[8], sv[9]),   cA1 = cvtpk(sv[10], sv[11]);
    unsigned cB0 = cvtpk(sv[12], sv[13]), cB1 = cvtpk(sv[14], sv[15]);
    unsigned w0, w1, w2, w3;
    plswap(cA0, cB0, w0, w2);
    plswap(cA1, cB1, w1, w3);
    u32x4 w = {w0, w1, w2, w3};
    fb = __builtin_bit_cast(s16x8, w);
  }
}

// ---------------- cast / pack kernel ----------------
__global__ __launch_bounds__(256) void cast_prep(
    const float* __restrict__ x, const float* __restrict__ wq,
    const float* __restrict__ wk, const float* __restrict__ wv,
    const float* __restrict__ wo, const float* __restrict__ bq,
    const float* __restrict__ bk, const float* __restrict__ bv,
    u16* __restrict__ xb, u16* __restrict__ wqkvb, u16* __restrict__ wob,
    float* __restrict__ bqkv) {
  int g = blockIdx.x * 256 + threadIdx.x;
  int e = g * 4;
  const float* src;
  u16* dst;
  if (e < NX) { src = x + e; dst = xb + e; }
  else {
    int e2 = e - NX;
    if (e2 < 3*NW) {
      const float* w = (e2 < NW) ? wq : (e2 < 2*NW ? wk : wv);
      int base = (e2 < NW) ? 0 : (e2 < 2*NW ? NW : 2*NW);
      src = w + (e2 - base); dst = wqkvb + e2;
    } else { int e3 = e2 - 3*NW; src = wo + e3; dst = wob + e3; }
  }
  float4 v = *(const float4*)src;
  ushort4 p;
  p.x = f2bf(v.x); p.y = f2bf(v.y); p.z = f2bf(v.z); p.w = f2bf(v.w);
  *(ushort4*)dst = p;
  if (blockIdx.x == 0) {
    for (int i = threadIdx.x; i < NQKV; i += 256)
      bqkv[i] = (i < DM) ? bq[i] : (i < 2*DM ? bk[i-DM] : bv[i-2*DM]);
  }
}

// ---------------- fused QKV GEMM: C = Xb @ Wqkv^T + b ----------------------
__global__ __launch_bounds__(256, 3) void gemm_qkv(
    const u16* __restrict__ A, const u16* __restrict__ W,
    const float* __restrict__ bias,
    u16* __restrict__ qb, u16* __restrict__ kb, u16* __restrict__ vt) {
  __shared__ __align__(16) u16 As[2][128*32], Bs[2][128*32];
  const int tid = threadIdx.x, lane = tid & 63, wave = tid >> 6;
  const int rg = lane & 15, cg = lane >> 4;
  int lin = blockIdx.y * 18 + blockIdx.x;
  int swz = (lin & 7) * 144 + (lin >> 3);
  const int m0 = (swz / 18) * 128, n0 = (swz % 18) * 128;
  const int wm = (wave >> 1) * 64, wn = (wave & 1) * 64;
  f32x4 acc[4][4];
#pragma unroll
  for (int i = 0; i < 4; i++)
#pragma unroll
    for (int j = 0; j < 4; j++) acc[i][j] = (f32x4){0.f,0.f,0.f,0.f};

  const u16* ga = A + (size_t)(m0 + (tid >> 2)) * DM + (tid & 3) * 8;
  const u16* gb = W + (size_t)(n0 + (tid >> 2)) * DM + (tid & 3) * 8;
  auto stage = [&](int kt, int buf) {
    int ko = kt * 32;
    char* la = (char*)&As[buf][0] + wave * 1024;
    char* lb = (char*)&Bs[buf][0] + wave * 1024;
    gload16(ga + ko,                    la);
    gload16(ga + (size_t)64*DM + ko,    la + 4096);
    gload16(gb + ko,                    lb);
    gload16(gb + (size_t)64*DM + ko,    lb + 4096);
  };

  stage(0, 0);
  __syncthreads();
  const int NT = DM / 32;  // 24
  int cur = 0;
  for (int kt = 0; kt < NT; ++kt) {
    if (kt + 1 < NT) stage(kt + 1, cur ^ 1);
    s16x8 af[4], bfv[4];
#pragma unroll
    for (int i = 0; i < 4; i++) af[i]  = *(const s16x8*)&As[cur][(wm + i*16 + rg)*32 + cg*8];
#pragma unroll
    for (int i = 0; i < 4; i++) bfv[i] = *(const s16x8*)&Bs[cur][(wn + i*16 + rg)*32 + cg*8];
    __builtin_amdgcn_s_setprio(1);
#pragma unroll
    for (int mi = 0; mi < 4; mi++)
#pragma unroll
      for (int ni = 0; ni < 4; ni++)
        acc[mi][ni] = __builtin_amdgcn_mfma_f32_16x16x32_bf16(af[mi], bfv[ni], acc[mi][ni], 0, 0, 0);
    __builtin_amdgcn_s_setprio(0);
    __syncthreads();
    cur ^= 1;
  }

#pragma unroll
  for (int ni = 0; ni < 4; ni++) {
    int o = n0 + wn + ni*16 + rg;
    float bia = bias[o];
    int mat = o / DM, d = o % DM;
    int head = d >> 6, dh = d & 63;
    if (mat == 2) {
#pragma unroll
      for (int mi = 0; mi < 4; mi++) {
        int m = m0 + wm + mi*16 + cg*4;
        int b = m >> 12, t = m & 4095;
        ushort4 pv;
        pv.x = f2bf(acc[mi][ni][0] + bia);
        pv.y = f2bf(acc[mi][ni][1] + bia);
        pv.z = f2bf(acc[mi][ni][2] + bia);
        pv.w = f2bf(acc[mi][ni][3] + bia);
        *(ushort4*)&vt[((size_t)((b*NH + head)*64 + dh))*TT + t] = pv;
      }
    } else {
      u16* outp = mat ? kb : qb;
      float sc = mat ? 1.0f : CEQ;   // fold softmax scale*log2e into Q
#pragma unroll
      for (int mi = 0; mi < 4; mi++) {
#pragma unroll
        for (int r = 0; r < 4; r++) {
          int m = m0 + wm + mi*16 + cg*4 + r;
          int b = m >> 12, t = m & 4095;
          outp[((size_t)((b*NH + head)*TT + t))*64 + dh] = f2bf((acc[mi][ni][r] + bia) * sc);
        }
      }
    }
  }
}

// ---------------- flash attention v10: 2-stage pipeline, 2 waves/SIMD ------
// r10's schedule (QK^T(j+1) under softmax(j), 3 buffers, counted vmcnt(2))
// with __launch_bounds__(256,2): the ~180-reg pipeline state (o + sA + sB in
// AGPRs, fragments in VGPRs) fits the 256 cap -> no scratch (r9/r10 spilled
// at the 168 cap of min-waves=3).
#define ATTN_LOADVF(bvp)                                                      \
  s16x8 vf0[4], vf1[4];                                                       \
  _Pragma("unroll")                                                           \
  for (int ks = 0; ks < 4; ++ks) {                                            \
    vf0[ks] = *(const s16x8*)((bvp) +        ((ks*32 + hi*16) ^ swb));        \
    vf1[ks] = *(const s16x8*)((bvp) + 4096 + ((ks*32 + hi*16) ^ swb));        \
  }

#define ATTN_QK(bkp, d0, d1)                                                  \
  {                                                                           \
    s16x8 kf0[4], kf1[4];                                                     \
    _Pragma("unroll")                                                         \
    for (int ds = 0; ds < 4; ++ds) {                                          \
      kf0[ds] = *(const s16x8*)((bkp) +        ((ds*32 + hi*16) ^ swb));      \
      kf1[ds] = *(const s16x8*)((bkp) + 4096 + ((ds*32 + hi*16) ^ swb));      \
    }                                                                         \
    d0 = (f32x16){}; d1 = (f32x16){};                                         \
    _Pragma("unroll")                                                         \
    for (int ds = 0; ds < 4; ++ds) {                                          \
      d0 = __builtin_amdgcn_mfma_f32_32x32x16_bf16(kf0[ds], qf[ds], d0, 0, 0, 0); \
      d1 = __builtin_amdgcn_mfma_f32_32x32x16_bf16(kf1[ds], qf[ds], d1, 0, 0, 0); \
    }                                                                         \
  }

#define ATTN_SMPV(c0, c1)                                                     \
  {                                                                           \
    _Pragma("unroll")                                                         \
    for (int i = 0; i < 16; ++i) c0[i] = EXP2(c0[i]);                         \
    _Pragma("unroll")                                                         \
    for (int i = 0; i < 16; ++i) c1[i] = EXP2(c1[i]);                         \
    f32x16 u = c0 + c1;                                                       \
    float a0 = u[0] + u[8],  a1 = u[1] + u[9],  a2 = u[2] + u[10], a3 = u[3] + u[11]; \
    float a4 = u[4] + u[12], a5 = u[5] + u[13], a6 = u[6] + u[14], a7 = u[7] + u[15]; \
    a0 += a4; a1 += a5; a2 += a6; a3 += a7;                                   \
    a0 += a2; a1 += a3;                                                       \
    L += a0 + a1;                                                             \
    s16x8 pf0, pf1, pf2, pf3;                                                 \
    repack2(c0, pf0, pf1);                                                    \
    repack2(c1, pf2, pf3);                                                    \
    __builtin_amdgcn_s_setprio(1);                                            \
    o0 = __builtin_amdgcn_mfma_f32_32x32x16_bf16(vf0[0], pf0, o0, 0, 0, 0);   \
    o1 = __builtin_amdgcn_mfma_f32_32x32x16_bf16(vf1[0], pf0, o1, 0, 0, 0);   \
    o0 = __builtin_amdgcn_mfma_f32_32x32x16_bf16(vf0[1], pf1, o0, 0, 0, 0);   \
    o1 = __builtin_amdgcn_mfma_f32_32x32x16_bf16(vf1[1], pf1, o1, 0, 0, 0);   \
    o0 = __builtin_amdgcn_mfma_f32_32x32x16_bf16(vf0[2], pf2, o0, 0, 0, 0);   \
    o1 = __builtin_amdgcn_mfma_f32_32x32x16_bf16(vf1[2], pf2, o1, 0, 0, 0);   \
    o0 = __builtin_amdgcn_mfma_f32_32x32x16_bf16(vf0[3], pf3, o0, 0, 0, 0);   \
    o1 = __builtin_amdgcn_mfma_f32_32x32x16_bf16(vf1[3], pf3, o1, 0, 0, 0);   \
    __builtin_amdgcn_s_setprio(0);                                            \
  }

__global__ __launch_bounds__(256, 2) void attn10(
    const u16* __restrict__ qg, const u16* __restrict__ kg,
    const u16* __restrict__ vtg, u16* __restrict__ h) {
  __shared__ __align__(16) char smem[49152];   // 3 x (K 8KB + V 8KB); epilogue reuses
  const int tid = threadIdx.x, lane = tid & 63, wave = tid >> 6;
  const int ql = lane & 31, hi = lane >> 5;
  // XCD-bijective swizzle: 768 blocks = 8 XCD * 96
  int lin = blockIdx.y * 32 + blockIdx.x;
  int swz = (lin & 7) * 96 + (lin >> 3);
  int qt = swz & 31, bh = swz >> 5;
  const int b = bh / NH, head = bh % NH;
  const size_t hb = (size_t)bh * TT * 64;

  // ---- Q fragments (one-time strided read; Q pre-scaled by CEQ) ----
  const int qrow = qt * 128 + wave * 32 + ql;
  const u16* qp = qg + hb + (size_t)qrow * 64 + hi * 8;
  s16x8 qf[4];
#pragma unroll
  for (int ds = 0; ds < 4; ++ds) qf[ds] = *(const s16x8*)(qp + ds * 16);

  // ---- staging geometry (linear LDS dest, XOR-swizzled source) ----
  const int lr = lane >> 3;
  const int lc = ((lane & 7) ^ lr) * 16;
  const char* kSrc = (const char*)(kg + hb) + lr * 128 + lc;
  const char* vSrc = (const char*)(vtg + hb) + (size_t)lr * 8192 + lc;
  auto stage = [&](int kt, int buf) {
    char* lk = smem + buf * 16384 + wave * 2048;
    char* lv = lk + 8192;
    const char* gk = kSrc + (size_t)kt * 8192 + wave * 2048;
    const char* gv = vSrc + (size_t)kt * 128 + (size_t)wave * 131072;
    gload16(gk,          lk);          // K first: needed one iter earlier
    gload16(gk + 1024,   lk + 1024);
    gload16(gv,          lv);          // V last: may stay in flight longer
    gload16(gv + 65536,  lv + 1024);
  };

  f32x16 o0 = {}, o1 = {};
  float L = 0.f;
  const int swb = (ql & 7) << 4;
  const int NKT = TT / 64;  // 64

  // prologue: tiles 0,1 issued; vmcnt(2) -> K0,V0,K1 ready (V1 in flight)
  stage(0, 0);
  stage(1, 1);
  asm volatile("s_waitcnt vmcnt(2)" ::: "memory");
  __builtin_amdgcn_s_barrier();

  f32x16 sA0, sA1, sB0, sB1;
  {
    const char* bk0 = smem + ql * 128;
    ATTN_QK(bk0, sA0, sA1)
  }

  int cur = 0;
  for (int j = 0; j < NKT; j += 2) {
    // ---------------- body A (tile j): consume sA, produce sB --------------
    {
      int sb = cur + 2; if (sb >= 3) sb -= 3;
      if (j + 2 < NKT) stage(j + 2, sb);
      int nx = cur + 1; if (nx >= 3) nx -= 3;
      const char* bv_ = smem + cur * 16384 + 8192 + ql * 128;
      ATTN_LOADVF(bv_)
      {  // QK^T(j+1) under softmax(j): always valid here (j+1 <= NKT-1)
        const char* bk_ = smem + nx * 16384 + ql * 128;
        __builtin_amdgcn_s_setprio(1);
        ATTN_QK(bk_, sB0, sB1)
        __builtin_amdgcn_s_setprio(0);
      }
      ATTN_SMPV(sA0, sA1)
      if (j + 2 < NKT) {
        asm volatile("s_waitcnt vmcnt(2)" ::: "memory");
      } else {
        asm volatile("s_waitcnt vmcnt(0)" ::: "memory");
      }
      __builtin_amdgcn_s_barrier();
      cur = nx;
    }
    // ---------------- body B (tile j+1): consume sB, produce sA ------------
    {
      int jj = j + 1;
      int sb = cur + 2; if (sb >= 3) sb -= 3;
      if (jj + 2 < NKT) stage(jj + 2, sb);
      int nx = cur + 1; if (nx >= 3) nx -= 3;
      const char* bv_ = smem + cur * 16384 + 8192 + ql * 128;
      ATTN_LOADVF(bv_)
      if (jj + 1 < NKT) {  // skip on the final tile
        const char* bk_ = smem + nx * 16384 + ql * 128;
        __builtin_amdgcn_s_setprio(1);
        ATTN_QK(bk_, sA0, sA1)
        __builtin_amdgcn_s_setprio(0);
      }
      ATTN_SMPV(sB0, sB1)
      if (jj + 2 < NKT) {
        asm volatile("s_waitcnt vmcnt(2)" ::: "memory");
      } else {
        asm volatile("s_waitcnt vmcnt(0)" ::: "memory");
      }
      __builtin_amdgcn_s_barrier();
      cur = nx;
    }
  }

  // epilogue: cross-half L, normalize, bf16-pack, LDS transpose, store
  float Lt = xhalf_sum(L);
  float inv = 1.f / Lt;
  u16 (*ot)[32][72] = (u16(*)[32][72])smem;   // reuse stage LDS (all waves synced)
#pragma unroll
  for (int db = 0; db < 2; ++db) {
    const f32x16& ov = db ? o1 : o0;
#pragma unroll
    for (int i = 0; i < 8; ++i) {
      unsigned w = cvtpk(ov[2*i] * inv, ov[2*i+1] * inv);
      int d = db*32 + ((2*i) & 3) + 8*((2*i) >> 2) + 4*hi;
      *(unsigned*)&ot[wave][ql][d] = w;
    }
  }
  __syncthreads();
  const u16* rowp = &ot[wave][ql][hi*32];
  u32x4 r0 = *(const u32x4*)(rowp);
  u32x4 r1 = *(const u32x4*)(rowp + 8);
  u32x4 r2 = *(const u32x4*)(rowp + 16);
  u32x4 r3 = *(const u32x4*)(rowp + 24);
  u16* dst = h + (size_t)(b*TT + qrow) * DM + head*64 + hi*32;
  *(u32x4*)(dst)      = r0;
  *(u32x4*)(dst + 8)  = r1;
  *(u32x4*)(dst + 16) = r2;
  *(u32x4*)(dst + 24) = r3;
}

// ---------------- output projection: out = H @ Wo^T + bo (fp32) -----------
__global__ __launch_bounds__(256, 3) void gemm_proj(
    const u16* __restrict__ A, const u16* __restrict__ W,
    const float* __restrict__ bias, float* __restrict__ out) {
  __shared__ __align__(16) u16 As[2][128*32], Bs[2][128*32];
  const int tid = threadIdx.x, lane = tid & 63, wave = tid >> 6;
  const int rg = lane & 15, cg = lane >> 4;
  int lin = blockIdx.y * 6 + blockIdx.x;
  int swz = (lin & 7) * 48 + (lin >> 3);
  const int m0 = (swz / 6) * 128, n0 = (swz % 6) * 128;
  const int wm = (wave >> 1) * 64, wn = (wave & 1) * 64;
  f32x4 acc[4][4];
#pragma unroll
  for (int i = 0; i < 4; i++)
#pragma unroll
    for (int j = 0; j < 4; j++) acc[i][j] = (f32x4){0.f,0.f,0.f,0.f};

  const u16* ga = A + (size_t)(m0 + (tid >> 2)) * DM + (tid & 3) * 8;
  const u16* gb = W + (size_t)(n0 + (tid >> 2)) * DM + (tid & 3) * 8;
  auto stage = [&](int kt, int buf) {
    int ko = kt * 32;
    char* la = (char*)&As[buf][0] + wave * 1024;
    char* lb = (char*)&Bs[buf][0] + wave * 1024;
    gload16(ga + ko,                    la);
    gload16(ga + (size_t)64*DM + ko,    la + 4096);
    gload16(gb + ko,                    lb);
    gload16(gb + (size_t)64*DM + ko,    lb + 4096);
  };

  stage(0, 0);
  __syncthreads();
  const int NT = DM / 32;
  int cur = 0;
  for (int kt = 0; kt < NT; ++kt) {
    if (kt + 1 < NT) stage(kt + 1, cur ^ 1);
    s16x8 af[4], bfv[4];
#pragma unroll
    for (int i = 0; i < 4; i++) af[i]  = *(const s16x8*)&As[cur][(wm + i*16 + rg)*32 + cg*8];
#pragma unroll
    for (int i = 0; i < 4; i++) bfv[i] = *(const s16x8*)&Bs[cur][(wn + i*16 + rg)*32 + cg*8];
    __builtin_amdgcn_s_setprio(1);
#pragma unroll
    for (int mi = 0; mi < 4; mi++)
#pragma unroll
      for (int ni = 0; ni < 4; ni++)
        acc[mi][ni] = __builtin_amdgcn_mfma_f32_16x16x32_bf16(af[mi], bfv[ni], acc[mi][ni], 0, 0, 0);
    __builtin_amdgcn_s_setprio(0);
    __syncthreads();
    cur ^= 1;
  }
#pragma unroll
  for (int ni = 0; ni < 4; ni++) {
    int o = n0 + wn + ni*16 + rg;
    float bia = bias[o];
#pragma unroll
    for (int mi = 0; mi < 4; mi++) {
#pragma unroll
      for (int r = 0; r < 4; r++) {
        int m = m0 + wm + mi*16 + cg*4 + r;
        out[(size_t)m * DM + o] = acc[mi][ni][r] + bia;
      }
    }
  }
}

extern "C" void kernel_launch(void* const* d_in, const int* in_sizes, int n_in,
                              void* d_out, int out_size, void* d_ws, size_t ws_size,
                              hipStream_t stream) {
  (void)in_sizes; (void)n_in; (void)out_size; (void)ws_size;
  const float* x  = (const float*)d_in[0];
  const float* Wq = (const float*)d_in[1];
  const float* bq = (const float*)d_in[2];
  const float* Wk = (const float*)d_in[3];
  const float* bk = (const float*)d_in[4];
  const float* Wv = (const float*)d_in[5];
  const float* bv = (const float*)d_in[6];
  const float* Wo = (const float*)d_in[7];
  const float* bo = (const float*)d_in[8];
  float* out = (float*)d_out;

  char* ws = (char*)d_ws;
  size_t off = 0;
  auto alloc = [&](size_t bytes) {
    char* p = ws + off;
    off = (off + bytes + 255) & ~(size_t)255;
    return p;
  };
  u16*   xb    = (u16*)alloc((size_t)NX * 2);      // reused as attn output H
  u16*   wqkvb = (u16*)alloc((size_t)3 * NW * 2);
  u16*   wob   = (u16*)alloc((size_t)NW * 2);
  float* bqkv  = (float*)alloc((size_t)NQKV * 4);
  u16*   qb    = (u16*)alloc((size_t)NX * 2);
  u16*   kb    = (u16*)alloc((size_t)NX * 2);
  u16*   vtb   = (u16*)alloc((size_t)NX * 2);
  u16*   hbuf  = xb;  // xb dead after gemm_qkv

  cast_prep<<<(NX + 4*NW) / 4 / 256, 256, 0, stream>>>(x, Wq, Wk, Wv, Wo, bq, bk, bv,
                                                       xb, wqkvb, wob, bqkv);
  gemm_qkv<<<dim3(18, 64), 256, 0, stream>>>(xb, wqkvb, bqkv, qb, kb, vtb);
  attn10<<<dim3(32, TB*NH), 256, 0, stream>>>(qb, kb, vtb, hbuf);
  gemm_proj<<<dim3(6, 64), 256, 0, stream>>>(hbuf, wob, bo, out);
}

// Round 12
// 192.288 us; speedup vs baseline: 3.6529x; 1.0548x over previous
//
#include <hip/hip_runtime.h>
#include <hip/hip_bf16.h>

#define DM 768
#define NH 12
#define TB 2
#define TT 4096
#define MM (TB*TT)        // 8192 tokens
#define NQKV (3*DM)       // 2304
#define NW (DM*DM)        // 589824
#define NX (MM*DM)        // 6291456
#define CEQ 0.18033688f   // 0.125 * log2(e), folded into Q

typedef unsigned short u16;
typedef short s16x8 __attribute__((ext_vector_type(8)));
typedef unsigned short u16x8 __attribute__((ext_vector_type(8)));
typedef float f32x4 __attribute__((ext_vector_type(4)));
typedef float f32x16 __attribute__((ext_vector_type(16)));
typedef unsigned u32x4 __attribute__((ext_vector_type(4)));

#if __has_builtin(__builtin_amdgcn_exp2f)
#define EXP2 __builtin_amdgcn_exp2f
#else
#define EXP2 exp2f
#endif

__device__ __forceinline__ u16 f2bf(float f) {
  unsigned u = __builtin_bit_cast(unsigned, f);
  unsigned r = (u + 0x7FFFu + ((u >> 16) & 1u)) >> 16;
  return (u16)r;
}

__device__ __forceinline__ unsigned cvtpk(float lo, float hi) {
  unsigned r;
  asm("v_cvt_pk_bf16_f32 %0, %1, %2" : "=v"(r) : "v"(lo), "v"(hi));
  return r;
}

// async global(16B/lane) -> LDS (wave-uniform base + lane*16); per-lane source
__device__ __forceinline__ void gload16(const void* g, void* l) {
  __builtin_amdgcn_global_load_lds(
      (const __attribute__((address_space(1))) void*)g,
      (__attribute__((address_space(3))) void*)l, 16, 0, 0);
}

// permlane32_swap(a,b) -> r0 = {l<32: a[l], l>=32: b[l-32]}
//                         r1 = {l<32: a[l+32], l>=32: b[l]}
__device__ __forceinline__ void plswap(unsigned a, unsigned b, unsigned& r0, unsigned& r1) {
#if __has_builtin(__builtin_amdgcn_permlane32_swap)
  auto rr = __builtin_amdgcn_permlane32_swap(a, b, false, false);
  unsigned tmp[2];
  __builtin_memcpy(tmp, &rr, 8);
  r0 = tmp[0]; r1 = tmp[1];
#else
  int hi_ = (threadIdx.x >> 5) & 1;
  unsigned bx = (unsigned)__shfl_xor((int)b, 32, 64);
  unsigned ax = (unsigned)__shfl_xor((int)a, 32, 64);
  r0 = hi_ ? bx : a;
  r1 = hi_ ? b : ax;
#endif
}

__device__ __forceinline__ float xhalf_sum(float v) {
  unsigned a = __builtin_bit_cast(unsigned, v), r0, r1;
  plswap(a, a, r0, r1);
  return __builtin_bit_cast(float, r0) + __builtin_bit_cast(float, r1);
}

// Repack one 32-key block of P^T (f32x16 per lane, key=crow(r,hi)=(r&3)+8*(r>>2)+4*hi)
// into two PV B-operand fragments (keys 0..15 -> fa, keys 16..31 -> fb).
__device__ __forceinline__ void repack2(const f32x16& sv, s16x8& fa, s16x8& fb) {
  {
    unsigned cA0 = cvtpk(sv[0], sv[1]),  cA1 = cvtpk(sv[2], sv[3]);
    unsigned cB0 = cvtpk(sv[4], sv[5]),  cB1 = cvtpk(sv[6], sv[7]);
    unsigned w0, w1, w2, w3;
    plswap(cA0, cB0, w0, w2);
    plswap(cA1, cB1, w1, w3);
    u32x4 w = {w0, w1, w2, w3};
    fa = __builtin_bit_cast(s16x8, w);
  }
  {
    unsigned cA0 = cvtpk(sv[8], sv[9]),   cA1 = cvtpk(sv[10], sv[11]);
    unsigned cB0 = cvtpk(sv[12], sv[13]), cB1 = cvtpk(sv[14], sv[15]);
    unsigned w0, w1, w2, w3;
    plswap(cA0, cB0, w0, w2);
    plswap(cA1, cB1, w1, w3);
    u32x4 w = {w0, w1, w2, w3};
    fb = __builtin_bit_cast(s16x8, w);
  }
}

// ---------------- cast / pack kernel ----------------
__global__ __launch_bounds__(256) void cast_prep(
    const float* __restrict__ x, const float* __restrict__ wq,
    const float* __restrict__ wk, const float* __restrict__ wv,
    const float* __restrict__ wo, const float* __restrict__ bq,
    const float* __restrict__ bk, const float* __restrict__ bv,
    u16* __restrict__ xb, u16* __restrict__ wqkvb, u16* __restrict__ wob,
    float* __restrict__ bqkv) {
  int g = blockIdx.x * 256 + threadIdx.x;
  int e = g * 4;
  const float* src;
  u16* dst;
  if (e < NX) { src = x + e; dst = xb + e; }
  else {
    int e2 = e - NX;
    if (e2 < 3*NW) {
      const float* w = (e2 < NW) ? wq : (e2 < 2*NW ? wk : wv);
      int base = (e2 < NW) ? 0 : (e2 < 2*NW ? NW : 2*NW);
      src = w + (e2 - base); dst = wqkvb + e2;
    } else { int e3 = e2 - 3*NW; src = wo + e3; dst = wob + e3; }
  }
  float4 v = *(const float4*)src;
  ushort4 p;
  p.x = f2bf(v.x); p.y = f2bf(v.y); p.z = f2bf(v.z); p.w = f2bf(v.w);
  *(ushort4*)dst = p;
  if (blockIdx.x == 0) {
    for (int i = threadIdx.x; i < NQKV; i += 256)
      bqkv[i] = (i < DM) ? bq[i] : (i < 2*DM ? bk[i-DM] : bv[i-2*DM]);
  }
}

// ---------------- fused QKV GEMM: C = Xb @ Wqkv^T + b ----------------------
__global__ __launch_bounds__(256, 3) void gemm_qkv(
    const u16* __restrict__ A, const u16* __restrict__ W,
    const float* __restrict__ bias,
    u16* __restrict__ qb, u16* __restrict__ kb, u16* __restrict__ vt) {
  __shared__ __align__(16) u16 As[2][128*32], Bs[2][128*32];
  const int tid = threadIdx.x, lane = tid & 63, wave = tid >> 6;
  const int rg = lane & 15, cg = lane >> 4;
  int lin = blockIdx.y * 18 + blockIdx.x;
  int swz = (lin & 7) * 144 + (lin >> 3);
  const int m0 = (swz / 18) * 128, n0 = (swz % 18) * 128;
  const int wm = (wave >> 1) * 64, wn = (wave & 1) * 64;
  f32x4 acc[4][4];
#pragma unroll
  for (int i = 0; i < 4; i++)
#pragma unroll
    for (int j = 0; j < 4; j++) acc[i][j] = (f32x4){0.f,0.f,0.f,0.f};

  const u16* ga = A + (size_t)(m0 + (tid >> 2)) * DM + (tid & 3) * 8;
  const u16* gb = W + (size_t)(n0 + (tid >> 2)) * DM + (tid & 3) * 8;
  auto stage = [&](int kt, int buf) {
    int ko = kt * 32;
    char* la = (char*)&As[buf][0] + wave * 1024;
    char* lb = (char*)&Bs[buf][0] + wave * 1024;
    gload16(ga + ko,                    la);
    gload16(ga + (size_t)64*DM + ko,    la + 4096);
    gload16(gb + ko,                    lb);
    gload16(gb + (size_t)64*DM + ko,    lb + 4096);
  };

  stage(0, 0);
  __syncthreads();
  const int NT = DM / 32;  // 24
  int cur = 0;
  for (int kt = 0; kt < NT; ++kt) {
    if (kt + 1 < NT) stage(kt + 1, cur ^ 1);
    s16x8 af[4], bfv[4];
#pragma unroll
    for (int i = 0; i < 4; i++) af[i]  = *(const s16x8*)&As[cur][(wm + i*16 + rg)*32 + cg*8];
#pragma unroll
    for (int i = 0; i < 4; i++) bfv[i] = *(const s16x8*)&Bs[cur][(wn + i*16 + rg)*32 + cg*8];
    __builtin_amdgcn_s_setprio(1);
#pragma unroll
    for (int mi = 0; mi < 4; mi++)
#pragma unroll
      for (int ni = 0; ni < 4; ni++)
        acc[mi][ni] = __builtin_amdgcn_mfma_f32_16x16x32_bf16(af[mi], bfv[ni], acc[mi][ni], 0, 0, 0);
    __builtin_amdgcn_s_setprio(0);
    __syncthreads();
    cur ^= 1;
  }

#pragma unroll
  for (int ni = 0; ni < 4; ni++) {
    int o = n0 + wn + ni*16 + rg;
    float bia = bias[o];
    int mat = o / DM, d = o % DM;
    int head = d >> 6, dh = d & 63;
    if (mat == 2) {
#pragma unroll
      for (int mi = 0; mi < 4; mi++) {
        int m = m0 + wm + mi*16 + cg*4;
        int b = m >> 12, t = m & 4095;
        ushort4 pv;
        pv.x = f2bf(acc[mi][ni][0] + bia);
        pv.y = f2bf(acc[mi][ni][1] + bia);
        pv.z = f2bf(acc[mi][ni][2] + bia);
        pv.w = f2bf(acc[mi][ni][3] + bia);
        *(ushort4*)&vt[((size_t)((b*NH + head)*64 + dh))*TT + t] = pv;
      }
    } else {
      u16* outp = mat ? kb : qb;
      float sc = mat ? 1.0f : CEQ;   // fold softmax scale*log2e into Q
#pragma unroll
      for (int mi = 0; mi < 4; mi++) {
#pragma unroll
        for (int r = 0; r < 4; r++) {
          int m = m0 + wm + mi*16 + cg*4 + r;
          int b = m >> 12, t = m & 4095;
          outp[((size_t)((b*NH + head)*TT + t))*64 + dh] = f2bf((acc[mi][ni][r] + bia) * sc);
        }
      }
    }
  }
}

// ---------------- flash attention v11: attn4 + conflict-free paired LDS ----
// attn4 structure (proven 124us) with tiles stored as [32 rows x 256B]:
// row r holds keys {2r,2r+1} (K) / d {2r,2r+1} (V); 16 slots of 16B, slot
// p = s ^ (r&15) where s = (k&1)*8 + chunk. Fragment reads: 32 lanes map to
// 16 slots exactly 2x -> 2-way (free, m136) vs the old 4-way (1.58x).
// global_load_lds keeps a linear dest; per-lane SOURCE gets the inverse map.
__global__ __launch_bounds__(256, 3) void attn11(
    const u16* __restrict__ qg, const u16* __restrict__ kg,
    const u16* __restrict__ vtg, u16* __restrict__ h) {
  __shared__ __align__(16) char smem[32768];   // 2 x (K 8KB + V 8KB); epilogue reuses
  const int tid = threadIdx.x, lane = tid & 63, wave = tid >> 6;
  const int ql = lane & 31, hi = lane >> 5;
  // XCD-bijective swizzle: 768 blocks = 8 XCD * 96
  int lin = blockIdx.y * 32 + blockIdx.x;
  int swz = (lin & 7) * 96 + (lin >> 3);
  int qt = swz & 31, bh = swz >> 5;
  const int b = bh / NH, head = bh % NH;
  const size_t hb = (size_t)bh * TT * 64;

  // ---- Q fragments (one-time strided read; Q pre-scaled by CEQ) ----
  const int qrow = qt * 128 + wave * 32 + ql;
  const u16* qp = qg + hb + (size_t)qrow * 64 + hi * 8;
  s16x8 qf[4];
#pragma unroll
  for (int ds = 0; ds < 4; ++ds) qf[ds] = *(const s16x8*)(qp + ds * 16);

  // ---- staging: per-lane source offsets via inverse of the paired layout --
  const char* kgB = (const char*)(kg + hb);
  const char* vgB = (const char*)(vtg + hb);
  const int o0 = wave * 2048 + lane * 16;       // dest off within tile, c=0
  const int o1 = o0 + 1024;                     // c=1
  const int r0 = o0 >> 8, s0 = ((o0 >> 4) & 15) ^ (r0 & 15);
  const int r1 = o1 >> 8, s1 = ((o1 >> 4) & 15) ^ (r1 & 15);
  const int    kOff0 = (2*r0 + (s0 >> 3)) * 128 + (s0 & 7) * 16;
  const int    kOff1 = (2*r1 + (s1 >> 3)) * 128 + (s1 & 7) * 16;
  const size_t vOff0 = (size_t)(2*r0 + (s0 >> 3)) * (TT*2) + (s0 & 7) * 16;
  const size_t vOff1 = (size_t)(2*r1 + (s1 >> 3)) * (TT*2) + (s1 & 7) * 16;
  auto stage = [&](int kt, int buf) {
    char* lk = smem + buf * 16384 + wave * 2048;
    char* lv = lk + 8192;
    const char* gkt = kgB + (size_t)kt * 8192;
    const char* gvt = vgB + (size_t)kt * 128;
    gload16(gkt + kOff0, lk);
    gload16(gkt + kOff1, lk + 1024);
    gload16(gvt + vOff0, lv);
    gload16(gvt + vOff1, lv + 1024);
  };

  f32x16 o0v = {}, o1v = {};
  float L = 0.f;
  // fragment-read constants (paired layout)
  const int kr = ql >> 1;            // row within 32-row half (0..15)
  const int kh = (ql & 1) << 3;      // parity half-slot

  stage(0, 0);
  __syncthreads();

  const int NKT = TT / 64;  // 64
  int cur = 0;
  for (int kt = 0; kt < NKT; ++kt) {
    if (kt + 1 < NKT) stage(kt + 1, cur ^ 1);

    const char* Kt = smem + cur * 16384;
    const char* bkr = Kt + kr * 256;
    const char* bvr = Kt + 8192 + kr * 256;

    // K fragments + S^T = K · Q^T  (D[key][q], q = ql per lane)
    s16x8 kf0[4], kf1[4];
#pragma unroll
    for (int ds = 0; ds < 4; ++ds) {
      int p = ((kh + 2*ds + hi) ^ kr) * 16;
      kf0[ds] = *(const s16x8*)(bkr + p);
      kf1[ds] = *(const s16x8*)(bkr + 4096 + p);
    }
    f32x16 sv0 = {}, sv1 = {};
    __builtin_amdgcn_s_setprio(1);
#pragma unroll
    for (int ds = 0; ds < 4; ++ds) {
      sv0 = __builtin_amdgcn_mfma_f32_32x32x16_bf16(kf0[ds], qf[ds], sv0, 0, 0, 0);
      sv1 = __builtin_amdgcn_mfma_f32_32x32x16_bf16(kf1[ds], qf[ds], sv1, 0, 0, 0);
    }
    __builtin_amdgcn_s_setprio(0);

    // V^T fragments (issue early; consumed after softmax)
    s16x8 vf0[4], vf1[4];
#pragma unroll
    for (int ks = 0; ks < 4; ++ks) {
      int p = ((kh + 2*ks + hi) ^ kr) * 16;
      vf0[ks] = *(const s16x8*)(bvr + p);
      vf1[ks] = *(const s16x8*)(bvr + 4096 + p);
    }

    // softmax numerator: p = exp2(s)  (scale folded into Q, no max needed)
#pragma unroll
    for (int i = 0; i < 16; ++i) sv0[i] = EXP2(sv0[i]);
#pragma unroll
    for (int i = 0; i < 16; ++i) sv1[i] = EXP2(sv1[i]);
    // pairwise-tree row sum (depth 4)
    f32x16 u = sv0 + sv1;
    float a0 = u[0] + u[8],  a1 = u[1] + u[9],  a2 = u[2] + u[10], a3 = u[3] + u[11];
    float a4 = u[4] + u[12], a5 = u[5] + u[13], a6 = u[6] + u[14], a7 = u[7] + u[15];
    a0 += a4; a1 += a5; a2 += a6; a3 += a7;
    a0 += a2; a1 += a3;
    L += a0 + a1;

    // repack P^T -> PV B-fragments (in-register: cvt_pk + permlane32_swap)
    s16x8 pf[4];
    repack2(sv0, pf[0], pf[1]);
    repack2(sv1, pf[2], pf[3]);

    // O^T += V^T · P : D[d][q]
    __builtin_amdgcn_s_setprio(1);
#pragma unroll
    for (int ks = 0; ks < 4; ++ks) {
      o0v = __builtin_amdgcn_mfma_f32_32x32x16_bf16(vf0[ks], pf[ks], o0v, 0, 0, 0);
      o1v = __builtin_amdgcn_mfma_f32_32x32x16_bf16(vf1[ks], pf[ks], o1v, 0, 0, 0);
    }
    __builtin_amdgcn_s_setprio(0);

    __syncthreads();   // stage(kt+1) complete; all waves done reading buf[cur]
    cur ^= 1;
  }

  // epilogue: cross-half L, normalize, bf16-pack, LDS transpose, store
  float Lt = xhalf_sum(L);
  float inv = 1.f / Lt;
  u16 (*ot)[32][72] = (u16(*)[32][72])smem;   // reuse stage LDS (all waves synced)
#pragma unroll
  for (int db = 0; db < 2; ++db) {
    const f32x16& ov = db ? o1v : o0v;
#pragma unroll
    for (int i = 0; i < 8; ++i) {
      unsigned w = cvtpk(ov[2*i] * inv, ov[2*i+1] * inv);
      int d = db*32 + ((2*i) & 3) + 8*((2*i) >> 2) + 4*hi;
      *(unsigned*)&ot[wave][ql][d] = w;
    }
  }
  __syncthreads();
  const u16* rowp = &ot[wave][ql][hi*32];
  u32x4 rr0 = *(const u32x4*)(rowp);
  u32x4 rr1 = *(const u32x4*)(rowp + 8);
  u32x4 rr2 = *(const u32x4*)(rowp + 16);
  u32x4 rr3 = *(const u32x4*)(rowp + 24);
  u16* dst = h + (size_t)(b*TT + qrow) * DM + head*64 + hi*32;
  *(u32x4*)(dst)      = rr0;
  *(u32x4*)(dst + 8)  = rr1;
  *(u32x4*)(dst + 16) = rr2;
  *(u32x4*)(dst + 24) = rr3;
}

// ---------------- output projection: out = H @ Wo^T + bo (fp32) -----------
__global__ __launch_bounds__(256, 3) void gemm_proj(
    const u16* __restrict__ A, const u16* __restrict__ W,
    const float* __restrict__ bias, float* __restrict__ out) {
  __shared__ __align__(16) u16 As[2][128*32], Bs[2][128*32];
  const int tid = threadIdx.x, lane = tid & 63, wave = tid >> 6;
  const int rg = lane & 15, cg = lane >> 4;
  int lin = blockIdx.y * 6 + blockIdx.x;
  int swz = (lin & 7) * 48 + (lin >> 3);
  const int m0 = (swz / 6) * 128, n0 = (swz % 6) * 128;
  const int wm = (wave >> 1) * 64, wn = (wave & 1) * 64;
  f32x4 acc[4][4];
#pragma unroll
  for (int i = 0; i < 4; i++)
#pragma unroll
    for (int j = 0; j < 4; j++) acc[i][j] = (f32x4){0.f,0.f,0.f,0.f};

  const u16* ga = A + (size_t)(m0 + (tid >> 2)) * DM + (tid & 3) * 8;
  const u16* gb = W + (size_t)(n0 + (tid >> 2)) * DM + (tid & 3) * 8;
  auto stage = [&](int kt, int buf) {
    int ko = kt * 32;
    char* la = (char*)&As[buf][0] + wave * 1024;
    char* lb = (char*)&Bs[buf][0] + wave * 1024;
    gload16(ga + ko,                    la);
    gload16(ga + (size_t)64*DM + ko,    la + 4096);
    gload16(gb + ko,                    lb);
    gload16(gb + (size_t)64*DM + ko,    lb + 4096);
  };

  stage(0, 0);
  __syncthreads();
  const int NT = DM / 32;
  int cur = 0;
  for (int kt = 0; kt < NT; ++kt) {
    if (kt + 1 < NT) stage(kt + 1, cur ^ 1);
    s16x8 af[4], bfv[4];
#pragma unroll
    for (int i = 0; i < 4; i++) af[i]  = *(const s16x8*)&As[cur][(wm + i*16 + rg)*32 + cg*8];
#pragma unroll
    for (int i = 0; i < 4; i++) bfv[i] = *(const s16x8*)&Bs[cur][(wn + i*16 + rg)*32 + cg*8];
    __builtin_amdgcn_s_setprio(1);
#pragma unroll
    for (int mi = 0; mi < 4; mi++)
#pragma unroll
      for (int ni = 0; ni < 4; ni++)
        acc[mi][ni] = __builtin_amdgcn_mfma_f32_16x16x32_bf16(af[mi], bfv[ni], acc[mi][ni], 0, 0, 0);
    __builtin_amdgcn_s_setprio(0);
    __syncthreads();
    cur ^= 1;
  }
#pragma unroll
  for (int ni = 0; ni < 4; ni++) {
    int o = n0 + wn + ni*16 + rg;
    float bia = bias[o];
#pragma unroll
    for (int mi = 0; mi < 4; mi++) {
#pragma unroll
      for (int r = 0; r < 4; r++) {
        int m = m0 + wm + mi*16 + cg*4 + r;
        out[(size_t)m * DM + o] = acc[mi][ni][r] + bia;
      }
    }
  }
}

extern "C" void kernel_launch(void* const* d_in, const int* in_sizes, int n_in,
                              void* d_out, int out_size, void* d_ws, size_t ws_size,
                              hipStream_t stream) {
  (void)in_sizes; (void)n_in; (void)out_size; (void)ws_size;
  const float* x  = (const float*)d_in[0];
  const float* Wq = (const float*)d_in[1];
  const float* bq = (const float*)d_in[2];
  const float* Wk = (const float*)d_in[3];
  const float* bk = (const float*)d_in[4];
  const float* Wv = (const float*)d_in[5];
  const float* bv = (const float*)d_in[6];
  const float* Wo = (const float*)d_in[7];
  const float* bo = (const float*)d_in[8];
  float* out = (float*)d_out;

  char* ws = (char*)d_ws;
  size_t off = 0;
  auto alloc = [&](size_t bytes) {
    char* p = ws + off;
    off = (off + bytes + 255) & ~(size_t)255;
    return p;
  };
  u16*   xb    = (u16*)alloc((size_t)NX * 2);      // reused as attn output H
  u16*   wqkvb = (u16*)alloc((size_t)3 * NW * 2);
  u16*   wob   = (u16*)alloc((size_t)NW * 2);
  float* bqkv  = (float*)alloc((size_t)NQKV * 4);
  u16*   qb    = (u16*)alloc((size_t)NX * 2);
  u16*   kb    = (u16*)alloc((size_t)NX * 2);
  u16*   vtb   = (u16*)alloc((size_t)NX * 2);
  u16*   hbuf  = xb;  // xb dead after gemm_qkv

  cast_prep<<<(NX + 4*NW) / 4 / 256, 256, 0, stream>>>(x, Wq, Wk, Wv, Wo, bq, bk, bv,
                                                       xb, wqkvb, wob, bqkv);
  gemm_qkv<<<dim3(18, 64), 256, 0, stream>>>(xb, wqkvb, bqkv, qb, kb, vtb);
  attn11<<<dim3(32, TB*NH), 256, 0, stream>>>(qb, kb, vtb, hbuf);
  gemm_proj<<<dim3(6, 64), 256, 0, stream>>>(hbuf, wob, bo, out);
}

// Round 15
// 192.078 us; speedup vs baseline: 3.6569x; 1.0011x over previous
//
#include <hip/hip_runtime.h>
#include <hip/hip_bf16.h>

#define DM 768
#define NH 12
#define TB 2
#define TT 4096
#define MM (TB*TT)        // 8192 tokens
#define NQKV (3*DM)       // 2304
#define NW (DM*DM)        // 589824
#define NX (MM*DM)        // 6291456
#define CEQ 0.18033688f   // 0.125 * log2(e), folded into Q

typedef unsigned short u16;
typedef short s16x8 __attribute__((ext_vector_type(8)));
typedef unsigned short u16x8 __attribute__((ext_vector_type(8)));
typedef float f32x4 __attribute__((ext_vector_type(4)));
typedef float f32x16 __attribute__((ext_vector_type(16)));
typedef unsigned u32x4 __attribute__((ext_vector_type(4)));

#if __has_builtin(__builtin_amdgcn_exp2f)
#define EXP2 __builtin_amdgcn_exp2f
#else
#define EXP2 exp2f
#endif

__device__ __forceinline__ u16 f2bf(float f) {
  unsigned u = __builtin_bit_cast(unsigned, f);
  unsigned r = (u + 0x7FFFu + ((u >> 16) & 1u)) >> 16;
  return (u16)r;
}

__device__ __forceinline__ unsigned cvtpk(float lo, float hi) {
  unsigned r;
  asm("v_cvt_pk_bf16_f32 %0, %1, %2" : "=v"(r) : "v"(lo), "v"(hi));
  return r;
}

// async global(16B/lane) -> LDS (wave-uniform base + lane*16); per-lane source
__device__ __forceinline__ void gload16(const void* g, void* l) {
  __builtin_amdgcn_global_load_lds(
      (const __attribute__((address_space(1))) void*)g,
      (__attribute__((address_space(3))) void*)l, 16, 0, 0);
}

// permlane32_swap(a,b) -> r0 = {l<32: a[l], l>=32: b[l-32]}
//                         r1 = {l<32: a[l+32], l>=32: b[l]}
__device__ __forceinline__ void plswap(unsigned a, unsigned b, unsigned& r0, unsigned& r1) {
#if __has_builtin(__builtin_amdgcn_permlane32_swap)
  auto rr = __builtin_amdgcn_permlane32_swap(a, b, false, false);
  unsigned tmp[2];
  __builtin_memcpy(tmp, &rr, 8);
  r0 = tmp[0]; r1 = tmp[1];
#else
  int hi_ = (threadIdx.x >> 5) & 1;
  unsigned bx = (unsigned)__shfl_xor((int)b, 32, 64);
  unsigned ax = (unsigned)__shfl_xor((int)a, 32, 64);
  r0 = hi_ ? bx : a;
  r1 = hi_ ? b : ax;
#endif
}

__device__ __forceinline__ float xhalf_sum(float v) {
  unsigned a = __builtin_bit_cast(unsigned, v), r0, r1;
  plswap(a, a, r0, r1);
  return __builtin_bit_cast(float, r0) + __builtin_bit_cast(float, r1);
}

// Repack one 32-key block of P^T (f32x16 per lane, key=crow(r,hi)=(r&3)+8*(r>>2)+4*hi)
// into two PV B-operand fragments (keys 0..15 -> fa, keys 16..31 -> fb).
__device__ __forceinline__ void repack2(const f32x16& sv, s16x8& fa, s16x8& fb) {
  {
    unsigned cA0 = cvtpk(sv[0], sv[1]),  cA1 = cvtpk(sv[2], sv[3]);
    unsigned cB0 = cvtpk(sv[4], sv[5]),  cB1 = cvtpk(sv[6], sv[7]);
    unsigned w0, w1, w2, w3;
    plswap(cA0, cB0, w0, w2);
    plswap(cA1, cB1, w1, w3);
    u32x4 w = {w0, w1, w2, w3};
    fa = __builtin_bit_cast(s16x8, w);
  }
  {
    unsigned cA0 = cvtpk(sv[8], sv[9]),   cA1 = cvtpk(sv[10], sv[11]);
    unsigned cB0 = cvtpk(sv[12], sv[13]), cB1 = cvtpk(sv[14], sv[15]);
    unsigned w0, w1, w2, w3;
    plswap(cA0, cB0, w0, w2);
    plswap(cA1, cB1, w1, w3);
    u32x4 w = {w0, w1, w2, w3};
    fb = __builtin_bit_cast(s16x8, w);
  }
}

// ---------------- cast / pack kernel ----------------
__global__ __launch_bounds__(256) void cast_prep(
    const float* __restrict__ x, const float* __restrict__ wq,
    const float* __restrict__ wk, const float* __restrict__ wv,
    const float* __restrict__ wo, const float* __restrict__ bq,
    const float* __restrict__ bk, const float* __restrict__ bv,
    u16* __restrict__ xb, u16* __restrict__ wqkvb, u16* __restrict__ wob,
    float* __restrict__ bqkv) {
  int g = blockIdx.x * 256 + threadIdx.x;
  int e = g * 4;
  const float* src;
  u16* dst;
  if (e < NX) { src = x + e; dst = xb + e; }
  else {
    int e2 = e - NX;
    if (e2 < 3*NW) {
      const float* w = (e2 < NW) ? wq : (e2 < 2*NW ? wk : wv);
      int base = (e2 < NW) ? 0 : (e2 < 2*NW ? NW : 2*NW);
      src = w + (e2 - base); dst = wqkvb + e2;
    } else { int e3 = e2 - 3*NW; src = wo + e3; dst = wob + e3; }
  }
  float4 v = *(const float4*)src;
  ushort4 p;
  p.x = f2bf(v.x); p.y = f2bf(v.y); p.z = f2bf(v.z); p.w = f2bf(v.w);
  *(ushort4*)dst = p;
  if (blockIdx.x == 0) {
    for (int i = threadIdx.x; i < NQKV; i += 256)
      bqkv[i] = (i < DM) ? bq[i] : (i < 2*DM ? bk[i-DM] : bv[i-2*DM]);
  }
}

// ---------------- fused QKV GEMM: C = Xb @ Wqkv^T + b ----------------------
__global__ __launch_bounds__(256, 3) void gemm_qkv(
    const u16* __restrict__ A, const u16* __restrict__ W,
    const float* __restrict__ bias,
    u16* __restrict__ qb, u16* __restrict__ kb, u16* __restrict__ vt) {
  __shared__ __align__(16) u16 As[2][128*32], Bs[2][128*32];
  const int tid = threadIdx.x, lane = tid & 63, wave = tid >> 6;
  const int rg = lane & 15, cg = lane >> 4;
  int lin = blockIdx.y * 18 + blockIdx.x;
  int swz = (lin & 7) * 144 + (lin >> 3);
  const int m0 = (swz / 18) * 128, n0 = (swz % 18) * 128;
  const int wm = (wave >> 1) * 64, wn = (wave & 1) * 64;
  f32x4 acc[4][4];
#pragma unroll
  for (int i = 0; i < 4; i++)
#pragma unroll
    for (int j = 0; j < 4; j++) acc[i][j] = (f32x4){0.f,0.f,0.f,0.f};

  const u16* ga = A + (size_t)(m0 + (tid >> 2)) * DM + (tid & 3) * 8;
  const u16* gb = W + (size_t)(n0 + (tid >> 2)) * DM + (tid & 3) * 8;
  auto stage = [&](int kt, int buf) {
    int ko = kt * 32;
    char* la = (char*)&As[buf][0] + wave * 1024;
    char* lb = (char*)&Bs[buf][0] + wave * 1024;
    gload16(ga + ko,                    la);
    gload16(ga + (size_t)64*DM + ko,    la + 4096);
    gload16(gb + ko,                    lb);
    gload16(gb + (size_t)64*DM + ko,    lb + 4096);
  };

  stage(0, 0);
  __syncthreads();
  const int NT = DM / 32;  // 24
  int cur = 0;
  for (int kt = 0; kt < NT; ++kt) {
    if (kt + 1 < NT) stage(kt + 1, cur ^ 1);
    s16x8 af[4], bfv[4];
#pragma unroll
    for (int i = 0; i < 4; i++) af[i]  = *(const s16x8*)&As[cur][(wm + i*16 + rg)*32 + cg*8];
#pragma unroll
    for (int i = 0; i < 4; i++) bfv[i] = *(const s16x8*)&Bs[cur][(wn + i*16 + rg)*32 + cg*8];
    __builtin_amdgcn_s_setprio(1);
#pragma unroll
    for (int mi = 0; mi < 4; mi++)
#pragma unroll
      for (int ni = 0; ni < 4; ni++)
        acc[mi][ni] = __builtin_amdgcn_mfma_f32_16x16x32_bf16(af[mi], bfv[ni], acc[mi][ni], 0, 0, 0);
    __builtin_amdgcn_s_setprio(0);
    __syncthreads();
    cur ^= 1;
  }

#pragma unroll
  for (int ni = 0; ni < 4; ni++) {
    int o = n0 + wn + ni*16 + rg;
    float bia = bias[o];
    int mat = o / DM, d = o % DM;
    int head = d >> 6, dh = d & 63;
    if (mat == 2) {
#pragma unroll
      for (int mi = 0; mi < 4; mi++) {
        int m = m0 + wm + mi*16 + cg*4;
        int b = m >> 12, t = m & 4095;
        ushort4 pv;
        pv.x = f2bf(acc[mi][ni][0] + bia);
        pv.y = f2bf(acc[mi][ni][1] + bia);
        pv.z = f2bf(acc[mi][ni][2] + bia);
        pv.w = f2bf(acc[mi][ni][3] + bia);
        *(ushort4*)&vt[((size_t)((b*NH + head)*64 + dh))*TT + t] = pv;
      }
    } else {
      u16* outp = mat ? kb : qb;
      float sc = mat ? 1.0f : CEQ;   // fold softmax scale*log2e into Q
#pragma unroll
      for (int mi = 0; mi < 4; mi++) {
#pragma unroll
        for (int r = 0; r < 4; r++) {
          int m = m0 + wm + mi*16 + cg*4 + r;
          int b = m >> 12, t = m & 4095;
          outp[((size_t)((b*NH + head)*TT + t))*64 + dh] = f2bf((acc[mi][ni][r] + bia) * sc);
        }
      }
    }
  }
}

// ---------------- flash attention v11: attn4 + conflict-free paired LDS ----
// Tiles stored as [32 rows x 256B]: row r holds keys {2r,2r+1} (K) / d
// {2r,2r+1} (V); 16 slots of 16B, slot p = s ^ (r&15). Fragment reads: 32
// lanes map to 16 slots exactly 2x -> 2-way (free) vs 4-way in the 128B-row
// layout. global_load_lds keeps a linear dest; per-lane SOURCE is the
// inverse map. No-max softmax (scale*log2e folded into Q).
__global__ __launch_bounds__(256, 3) void attn11(
    const u16* __restrict__ qg, const u16* __restrict__ kg,
    const u16* __restrict__ vtg, u16* __restrict__ h) {
  __shared__ __align__(16) char smem[32768];   // 2 x (K 8KB + V 8KB); epilogue reuses
  const int tid = threadIdx.x, lane = tid & 63, wave = tid >> 6;
  const int ql = lane & 31, hi = lane >> 5;
  // XCD-bijective swizzle: 768 blocks = 8 XCD * 96
  int lin = blockIdx.y * 32 + blockIdx.x;
  int swz = (lin & 7) * 96 + (lin >> 3);
  int qt = swz & 31, bh = swz >> 5;
  const int b = bh / NH, head = bh % NH;
  const size_t hb = (size_t)bh * TT * 64;

  // ---- Q fragments (one-time strided read; Q pre-scaled by CEQ) ----
  const int qrow = qt * 128 + wave * 32 + ql;
  const u16* qp = qg + hb + (size_t)qrow * 64 + hi * 8;
  s16x8 qf[4];
#pragma unroll
  for (int ds = 0; ds < 4; ++ds) qf[ds] = *(const s16x8*)(qp + ds * 16);

  // ---- staging: per-lane source offsets via inverse of the paired layout --
  const char* kgB = (const char*)(kg + hb);
  const char* vgB = (const char*)(vtg + hb);
  const int o0 = wave * 2048 + lane * 16;       // dest off within tile, c=0
  const int o1 = o0 + 1024;                     // c=1
  const int r0 = o0 >> 8, s0i = ((o0 >> 4) & 15) ^ (r0 & 15);
  const int r1 = o1 >> 8, s1i = ((o1 >> 4) & 15) ^ (r1 & 15);
  const int    kOff0 = (2*r0 + (s0i >> 3)) * 128 + (s0i & 7) * 16;
  const int    kOff1 = (2*r1 + (s1i >> 3)) * 128 + (s1i & 7) * 16;
  const size_t vOff0 = (size_t)(2*r0 + (s0i >> 3)) * (TT*2) + (s0i & 7) * 16;
  const size_t vOff1 = (size_t)(2*r1 + (s1i >> 3)) * (TT*2) + (s1i & 7) * 16;
  auto stage = [&](int kt, int buf) {
    char* lk = smem + buf * 16384 + wave * 2048;
    char* lv = lk + 8192;
    const char* gkt = kgB + (size_t)kt * 8192;
    const char* gvt = vgB + (size_t)kt * 128;
    gload16(gkt + kOff0, lk);
    gload16(gkt + kOff1, lk + 1024);
    gload16(gvt + vOff0, lv);
    gload16(gvt + vOff1, lv + 1024);
  };

  f32x16 o0v = {}, o1v = {};
  float L = 0.f;
  // fragment-read constants (paired layout)
  const int kr = ql >> 1;            // row within 32-row half (0..15)
  const int kh = (ql & 1) << 3;      // parity half-slot

  stage(0, 0);
  __syncthreads();

  const int NKT = TT / 64;  // 64
  int cur = 0;
  for (int kt = 0; kt < NKT; ++kt) {
    if (kt + 1 < NKT) stage(kt + 1, cur ^ 1);

    const char* Kt = smem + cur * 16384;
    const char* bkr = Kt + kr * 256;
    const char* bvr = Kt + 8192 + kr * 256;

    // K fragments + S^T = K · Q^T  (D[key][q], q = ql per lane)
    s16x8 kf0[4], kf1[4];
#pragma unroll
    for (int ds = 0; ds < 4; ++ds) {
      int p = ((kh + 2*ds + hi) ^ kr) * 16;
      kf0[ds] = *(const s16x8*)(bkr + p);
      kf1[ds] = *(const s16x8*)(bkr + 4096 + p);
    }
    f32x16 sv0 = {}, sv1 = {};
    __builtin_amdgcn_s_setprio(1);
#pragma unroll
    for (int ds = 0; ds < 4; ++ds) {
      sv0 = __builtin_amdgcn_mfma_f32_32x32x16_bf16(kf0[ds], qf[ds], sv0, 0, 0, 0);
      sv1 = __builtin_amdgcn_mfma_f32_32x32x16_bf16(kf1[ds], qf[ds], sv1, 0, 0, 0);
    }
    __builtin_amdgcn_s_setprio(0);

    // V^T fragments (issue early; consumed after softmax)
    s16x8 vf0[4], vf1[4];
#pragma unroll
    for (int ks = 0; ks < 4; ++ks) {
      int p = ((kh + 2*ks + hi) ^ kr) * 16;
      vf0[ks] = *(const s16x8*)(bvr + p);
      vf1[ks] = *(const s16x8*)(bvr + 4096 + p);
    }

    // softmax numerator: p = exp2(s)  (scale folded into Q, no max needed)
#pragma unroll
    for (int i = 0; i < 16; ++i) sv0[i] = EXP2(sv0[i]);
#pragma unroll
    for (int i = 0; i < 16; ++i) sv1[i] = EXP2(sv1[i]);
    // pairwise-tree row sum (depth 4)
    f32x16 u = sv0 + sv1;
    float a0 = u[0] + u[8],  a1 = u[1] + u[9],  a2 = u[2] + u[10], a3 = u[3] + u[11];
    float a4 = u[4] + u[12], a5 = u[5] + u[13], a6 = u[6] + u[14], a7 = u[7] + u[15];
    a0 += a4; a1 += a5; a2 += a6; a3 += a7;
    a0 += a2; a1 += a3;
    L += a0 + a1;

    // repack P^T -> PV B-fragments (in-register: cvt_pk + permlane32_swap)
    s16x8 pf[4];
    repack2(sv0, pf[0], pf[1]);
    repack2(sv1, pf[2], pf[3]);

    // O^T += V^T · P : D[d][q]
    __builtin_amdgcn_s_setprio(1);
#pragma unroll
    for (int ks = 0; ks < 4; ++ks) {
      o0v = __builtin_amdgcn_mfma_f32_32x32x16_bf16(vf0[ks], pf[ks], o0v, 0, 0, 0);
      o1v = __builtin_amdgcn_mfma_f32_32x32x16_bf16(vf1[ks], pf[ks], o1v, 0, 0, 0);
    }
    __builtin_amdgcn_s_setprio(0);

    __syncthreads();   // stage(kt+1) complete; all waves done reading buf[cur]
    cur ^= 1;
  }

  // epilogue: cross-half L, normalize, bf16-pack, LDS transpose, store
  float Lt = xhalf_sum(L);
  float inv = 1.f / Lt;
  u16 (*ot)[32][72] = (u16(*)[32][72])smem;   // reuse stage LDS (all waves synced)
#pragma unroll
  for (int db = 0; db < 2; ++db) {
    const f32x16& ov = db ? o1v : o0v;
#pragma unroll
    for (int i = 0; i < 8; ++i) {
      unsigned w = cvtpk(ov[2*i] * inv, ov[2*i+1] * inv);
      int d = db*32 + ((2*i) & 3) + 8*((2*i) >> 2) + 4*hi;
      *(unsigned*)&ot[wave][ql][d] = w;
    }
  }
  __syncthreads();
  const u16* rowp = &ot[wave][ql][hi*32];
  u32x4 rr0 = *(const u32x4*)(rowp);
  u32x4 rr1 = *(const u32x4*)(rowp + 8);
  u32x4 rr2 = *(const u32x4*)(rowp + 16);
  u32x4 rr3 = *(const u32x4*)(rowp + 24);
  u16* dst = h + (size_t)(b*TT + qrow) * DM + head*64 + hi*32;
  *(u32x4*)(dst)      = rr0;
  *(u32x4*)(dst + 8)  = rr1;
  *(u32x4*)(dst + 16) = rr2;
  *(u32x4*)(dst + 24) = rr3;
}

// ---------------- output projection: out = H @ Wo^T + bo (fp32) -----------
__global__ __launch_bounds__(256, 3) void gemm_proj(
    const u16* __restrict__ A, const u16* __restrict__ W,
    const float* __restrict__ bias, float* __restrict__ out) {
  __shared__ __align__(16) u16 As[2][128*32], Bs[2][128*32];
  const int tid = threadIdx.x, lane = tid & 63, wave = tid >> 6;
  const int rg = lane & 15, cg = lane >> 4;
  int lin = blockIdx.y * 6 + blockIdx.x;
  int swz = (lin & 7) * 48 + (lin >> 3);
  const int m0 = (swz / 6) * 128, n0 = (swz % 6) * 128;
  const int wm = (wave >> 1) * 64, wn = (wave & 1) * 64;
  f32x4 acc[4][4];
#pragma unroll
  for (int i = 0; i < 4; i++)
#pragma unroll
    for (int j = 0; j < 4; j++) acc[i][j] = (f32x4){0.f,0.f,0.f,0.f};

  const u16* ga = A + (size_t)(m0 + (tid >> 2)) * DM + (tid & 3) * 8;
  const u16* gb = W + (size_t)(n0 + (tid >> 2)) * DM + (tid & 3) * 8;
  auto stage = [&](int kt, int buf) {
    int ko = kt * 32;
    char* la = (char*)&As[buf][0] + wave * 1024;
    char* lb = (char*)&Bs[buf][0] + wave * 1024;
    gload16(ga + ko,                    la);
    gload16(ga + (size_t)64*DM + ko,    la + 4096);
    gload16(gb + ko,                    lb);
    gload16(gb + (size_t)64*DM + ko,    lb + 4096);
  };

  stage(0, 0);
  __syncthreads();
  const int NT = DM / 32;
  int cur = 0;
  for (int kt = 0; kt < NT; ++kt) {
    if (kt + 1 < NT) stage(kt + 1, cur ^ 1);
    s16x8 af[4], bfv[4];
#pragma unroll
    for (int i = 0; i < 4; i++) af[i]  = *(const s16x8*)&As[cur][(wm + i*16 + rg)*32 + cg*8];
#pragma unroll
    for (int i = 0; i < 4; i++) bfv[i] = *(const s16x8*)&Bs[cur][(wn + i*16 + rg)*32 + cg*8];
    __builtin_amdgcn_s_setprio(1);
#pragma unroll
    for (int mi = 0; mi < 4; mi++)
#pragma unroll
      for (int ni = 0; ni < 4; ni++)
        acc[mi][ni] = __builtin_amdgcn_mfma_f32_16x16x32_bf16(af[mi], bfv[ni], acc[mi][ni], 0, 0, 0);
    __builtin_amdgcn_s_setprio(0);
    __syncthreads();
    cur ^= 1;
  }
#pragma unroll
  for (int ni = 0; ni < 4; ni++) {
    int o = n0 + wn + ni*16 + rg;
    float bia = bias[o];
#pragma unroll
    for (int mi = 0; mi < 4; mi++) {
#pragma unroll
      for (int r = 0; r < 4; r++) {
        int m = m0 + wm + mi*16 + cg*4 + r;
        out[(size_t)m * DM + o] = acc[mi][ni][r] + bia;
      }
    }
  }
}

extern "C" void kernel_launch(void* const* d_in, const int* in_sizes, int n_in,
                              void* d_out, int out_size, void* d_ws, size_t ws_size,
                              hipStream_t stream) {
  (void)in_sizes; (void)n_in; (void)out_size; (void)ws_size;
  const float* x  = (const float*)d_in[0];
  const float* Wq = (const float*)d_in[1];
  const float* bq = (const float*)d_in[2];
  const float* Wk = (const float*)d_in[3];
  const float* bk = (const float*)d_in[4];
  const float* Wv = (const float*)d_in[5];
  const float* bv = (const float*)d_in[6];
  const float* Wo = (const float*)d_in[7];
  const float* bo = (const float*)d_in[8];
  float* out = (float*)d_out;

  char* ws = (char*)d_ws;
  size_t off = 0;
  auto alloc = [&](size_t bytes) {
    char* p = ws + off;
    off = (off + bytes + 255) & ~(size_t)255;
    return p;
  };
  u16*   xb    = (u16*)alloc((size_t)NX * 2);      // reused as attn output H
  u16*   wqkvb = (u16*)alloc((size_t)3 * NW * 2);
  u16*   wob   = (u16*)alloc((size_t)NW * 2);
  float* bqkv  = (float*)alloc((size_t)NQKV * 4);
  u16*   qb    = (u16*)alloc((size_t)NX * 2);
  u16*   kb    = (u16*)alloc((size_t)NX * 2);
  u16*   vtb   = (u16*)alloc((size_t)NX * 2);
  u16*   hbuf  = xb;  // xb dead after gemm_qkv

  cast_prep<<<(NX + 4*NW) / 4 / 256, 256, 0, stream>>>(x, Wq, Wk, Wv, Wo, bq, bk, bv,
                                                       xb, wqkvb, wob, bqkv);
  gemm_qkv<<<dim3(18, 64), 256, 0, stream>>>(xb, wqkvb, bqkv, qb, kb, vtb);
  attn11<<<dim3(32, TB*NH), 256, 0, stream>>>(qb, kb, vtb, hbuf);
  gemm_proj<<<dim3(6, 64), 256, 0, stream>>>(hbuf, wob, bo, out);
}